// Round 11
// baseline (819.817 us; speedup 1.0000x reference)
//
#include <hip/hip_runtime.h>

#define HH 256
#define WW 256
#define NPIX (HH*WW)
#define LL 16
#define NL (NPIX*LL)
#define PP 136
#define PP2 (PP*2)

typedef _Float16 half_t;
typedef __attribute__((ext_vector_type(8))) _Float16 half8;

// constants (double-evaluated, cast to float -- matches JAX weak-typed scalars)
static constexpr float SIGMAP_F = (float)((1.0/256.0)/(3.0+16.0)); // res/(3+l)
static constexpr float TAUU_F   = (float)((1.0/256.0)/6.0);        // res/6
static constexpr float TAU_F    = (float)(1.0/36.0);               // 1/(2+136/4)

__device__ __forceinline__ float clampf(float x, float lo, float hi){
    return fminf(fmaxf(x, lo), hi);
}
__device__ __forceinline__ half8 h8zero() {
    half8 v;
    #pragma unroll
    for (int i = 0; i < 8; ++i) v[i] = (half_t)0.0f;
    return v;
}

// ---------------- prox: dual p update, vectorized half8 ----------------------
// thread = (pixel n, z-half hf): 8 consecutive z. All fp16 state loaded as
// half8 (G13: ~9 vector loads replace ~36 scalar loads). Math fp32, per-z.
// MODE 0 (it=0): state analytically zero, reads ONLY f (z-uniform gradients).
template<int MODE>
__global__ __launch_bounds__(256) void k_prox(const float* __restrict__ f,
    const half_t* __restrict__ ubar,
    const half_t* __restrict__ pxOld,   // px(it-1)
    half_t* __restrict__ pxCur,         // px(it) out
    half_t* __restrict__ pt,            // in-place
    const half_t* __restrict__ musum,   // [d][n][z]
    float* __restrict__ nrj)
{
    int t = blockIdx.x*256 + threadIdx.x;   // [0, 2*NPIX)
    if (MODE == 0 && t == 0) *nrj = 0.0f;
    int n  = t >> 1;
    int hf = t & 1;
    int z0 = hf << 3;
    int i = n >> 8, j = n & (WW-1);
    bool iok = (i < HH-1), jok = (j < WW-1);
    size_t base = (size_t)n*LL + z0;

    float fv = f[n];
    float g0c = 0.0f, g1c = 0.0f;
    half8 ubv = h8zero(), ubi = h8zero(), ubj = h8zero();
    float ubz8 = 0.0f;
    half8 ms0v = h8zero(), ms1v = h8zero();
    half8 p0v  = h8zero(), p1v  = h8zero(), ptv = h8zero();
    if (MODE == 0) {
        g0c = iok ? (f[n + WW] - fv) * 256.0f : 0.0f;
        g1c = jok ? (f[n + 1]  - fv) * 256.0f : 0.0f;
    } else {
        ubv = *reinterpret_cast<const half8*>(ubar + base);
        if (iok) ubi = *reinterpret_cast<const half8*>(ubar + base + (size_t)WW*LL);
        if (jok) ubj = *reinterpret_cast<const half8*>(ubar + base + LL);
        if (hf == 0) ubz8 = (float)ubar[base + 8];
        ms0v = *reinterpret_cast<const half8*>(musum + base);
        ms1v = *reinterpret_cast<const half8*>(musum + NL + base);
        p0v  = *reinterpret_cast<const half8*>(pxOld + base);
        p1v  = *reinterpret_cast<const half8*>(pxOld + NL + base);
        ptv  = *reinterpret_cast<const half8*>(pt + base);
    }

    half8 o0, o1, opt;
    #pragma unroll
    for (int e = 0; e < 8; ++e) {
        int z = z0 + e;
        float ux0, ux1, ut;
        if (MODE == 0) {
            ux0 = SIGMAP_F * g0c;
            ux1 = SIGMAP_F * g1c;
            ut  = 0.0f;
        } else {
            float ub = (float)ubv[e];
            float g0 = iok ? ((float)ubi[e] - ub) * 256.0f : 0.0f;
            float g1 = jok ? ((float)ubj[e] - ub) * 256.0f : 0.0f;
            float ubn = (e < 7) ? (float)ubv[e+1] : ubz8;
            float gt = (z < LL-1) ? (ubn - ub) * 16.0f : 0.0f;
            ux0 = (float)p0v[e] + SIGMAP_F * (g0 + (float)ms0v[e]);
            ux1 = (float)p1v[e] + SIGMAP_F * (g1 + (float)ms1v[e]);
            ut  = (float)ptv[e] + SIGMAP_F * gt;
        }

        float klf = (float)(z + 1) * 0.0625f - fv;
        float pen = 0.5f * klf * klf;            // lmbda = 0.5

        float n2 = ux0*ux0 + ux1*ux1;
        float B  = 0.25f * n2 - pen;
        bool mask = ut < B;

        float px0 = ux0, px1 = ux1, ptn = ut;
        if (mask) {
            float y    = ut + pen;
            float norm = sqrtf(n2);
            float a    = 0.5f * norm;
            float b    = (2.0f/3.0f) * (1.0f - 0.5f*y);
            float v;
            if (b < 0.0f) {
                float sb  = sqrtf(-b);
                float sb3 = sb*sb*sb;
                float dd  = (a - sb3)*(a + sb3);
                if (dd < 0.0f) {
                    float ratio = clampf(a / sb3, -1.0f, 1.0f);
                    v = 2.0f * sb * cosf(acosf(ratio) * (1.0f/3.0f));
                } else {
                    float c = cbrtf(a + sqrtf(dd));
                    v = (c == 0.0f) ? 0.0f : (c - b/c);
                }
            } else {
                float dd = a*a + b*b*b;          // >= 0
                float c  = cbrtf(a + sqrtf(dd));
                v = (c == 0.0f) ? 0.0f : (c - b/c);
            }
            if (norm == 0.0f) { px0 = 0.0f; px1 = 0.0f; }
            else              { float s = 2.0f*v/norm; px0 = s*ux0; px1 = s*ux1; }
            ptn = 0.25f*(px0*px0 + px1*px1) - pen;
        }
        o0[e]  = (half_t)px0;
        o1[e]  = (half_t)px1;
        opt[e] = (half_t)ptn;
    }
    *reinterpret_cast<half8*>(pxCur + base)      = o0;
    *reinterpret_cast<half8*>(pxCur + NL + base) = o1;
    *reinterpret_cast<half8*>(pt + base)         = opt;
}

// ---------------- fused s/mu update + primal u update ------------------------
// sx ELIMINATED: sx_{k-1} = (mu_{k-1}-mu_{k-2})/tau + t_prev (t_prev from
// pxOld). mubar = 2*mu_{k-1}-mu_{k-2}; mu ping-pong, only mu_k written.
// MODE 0: mu,pxOld zero (regs zero-init, loads skipped); MODE 1: muO zero.
// C[16] accumulator ELIMINATED: combo (a,b) covers a<=z<=b, so per-row
// contribution to musum[z] is the SUFFIX sum over b>=z of mn -- computed by a
// second unrolled descending pass over the mn registers (saves 16 VGPR, the
// key to the (512,8) / <=64-VGPR occupancy target).
template<int H, int MODE>
__device__ __forceinline__ void do_set(int d, int n, int lane,
    half8 ph0, half8 ph1, half8 pp0, half8 pp1,
    const half_t* __restrict__ muC,   // mu_{k-1} (read, MODE>=1)
    half_t* __restrict__ muO,         // mu_{k-2} (read, MODE 2) -> mu_k (write)
    float* __restrict__ part)
{
    constexpr size_t setbase = (size_t)H * 17 * 2 * NPIX;
    const size_t vb   = setbase + (size_t)n*16 + (size_t)d*8;    // chunk0
    const size_t vb1  = vb + (size_t)16*NPIX;                    // chunk1
    const size_t tail = setbase + (size_t)32*NPIX + (size_t)n*2 + (size_t)d;

    half8 mCv0 = h8zero(), mCv1 = h8zero(), mOv0 = h8zero(), mOv1 = h8zero();
    float mCT = 0.0f, mOT = 0.0f;
    if (MODE >= 1) {
        mCv0 = *reinterpret_cast<const half8*>(&muC[vb]);
        mCv1 = *reinterpret_cast<const half8*>(&muC[vb1]);
        mCT  = (float)muC[tail];
    }
    if (MODE == 2) {
        mOv0 = *reinterpret_cast<const half8*>(&muO[vb]);
        mOv1 = *reinterpret_cast<const half8*>(&muO[vb1]);
        mOT  = (float)muO[tail];
    }

    half8 muo0, muo1;
    half_t muoT = (half_t)0.0f;

    float tsum = 0.0f, tprev = 0.0f;
    #pragma unroll
    for (int q = 0; q < 17; ++q) {
        const int b = (q <= 15-H) ? H + q : q - 1;   // static under unroll
        float mC, mO;
        if (q < 8)       { mC=(float)mCv0[q];   mO=(float)mOv0[q]; }
        else if (q < 16) { mC=(float)mCv1[q-8]; mO=(float)mOv1[q-8]; }
        else             { mC=mCT;              mO=mOT; }

        if (q == 0 || q == 16-H) { tsum = 0.0f; tprev = 0.0f; }  // row start
        tsum  += (b < 8) ? (float)ph0[b] : (float)ph1[b-8];
        if (MODE >= 1)
            tprev += (b < 8) ? (float)pp0[b] : (float)pp1[b-8];

        // sx_{k-1} = (mu_{k-1}-mu_{k-2})/tau + t_prev ; mx = sx - mubar
        float sxp = (mC - mO) * 36.0f + tprev;
        float mx  = sxp - (2.0f*mC - mO);
        float mo  = __shfl_xor(mx, 1);
        float snorm = sqrtf(mx*mx + mo*mo);
        if (snorm > 25.6f) mx *= 0.1f / snorm;       // nu*H ; nu/snorm
        float mn = mC + TAU_F*(mx - tsum);

        if (q < 8)       muo0[q]   = (half_t)mn;
        else if (q < 16) muo1[q-8] = (half_t)mn;
        else             muoT      = (half_t)mn;
    }

    *reinterpret_cast<half8*>(&muO[vb])  = muo0;
    *reinterpret_cast<half8*>(&muO[vb1]) = muo1;
    muO[tail] = muoT;

    // suffix-sum pass: row H has b=z at q=z-H; row 15-H has b=z at q=z+1.
    float sA = 0.0f, sB = 0.0f;
    #pragma unroll
    for (int z = 15; z >= 0; --z) {
        float m = 0.0f;
        if (z >= H) {
            const int q = z - H;
            sA += (q < 8) ? (float)muo0[q] : (q < 16) ? (float)muo1[q-8] : (float)muoT;
            m += sA;
        }
        if (z >= 15-H) {
            const int q = z + 1;
            sB += (q < 8) ? (float)muo0[q] : (q < 16) ? (float)muo1[q-8] : (float)muoT;
            m += sB;
        }
        part[H*1024 + z*64 + lane] = m;
    }
}

template<int MODE>
__global__ __launch_bounds__(512, 8) void k_smu_u(
    const float* __restrict__ f,
    const half_t* __restrict__ pxCur,   // px(it)   [d][n][z] fp16
    const half_t* __restrict__ pxOld,   // px(it-1) (MODE>=1)
    const half_t* __restrict__ pt,
    const half_t* __restrict__ muC,     // mu_{k-1} (MODE>=1)
    half_t* __restrict__ muO,           // mu_{k-2} -> mu_k
    half_t* __restrict__ musum,         // [d][n][z] fp16 output
    float* __restrict__ u, half_t* __restrict__ ubar,
    float* __restrict__ out,            // final-iter u destination
    float* __restrict__ nrj, int last)
{
    __shared__ float part[8192];   // 32 KB: [h][z][lane], all slots written
    __shared__ float wsum[8];

    int tid  = threadIdx.x;
    int wv   = tid >> 6;          // wave id = row-set h (0..7)
    int lane = tid & 63;
    int pix  = lane >> 1;
    int d    = lane & 1;
    int n    = blockIdx.x*32 + pix;

    // -------- phase A inputs, packed half8 --------
    const half8* pv = reinterpret_cast<const half8*>(pxCur + (size_t)d*NL + (size_t)n*LL);
    half8 ph0 = pv[0], ph1 = pv[1];
    half8 pp0 = h8zero(), pp1 = h8zero();
    if (MODE >= 1) {
        const half8* ppv = reinterpret_cast<const half8*>(pxOld + (size_t)d*NL + (size_t)n*LL);
        pp0 = ppv[0]; pp1 = ppv[1];
    }

    // -------- phase A: s & mu (per wave = one row set) --------
    if      (wv == 0) do_set<0,MODE>(d,n,lane,ph0,ph1,pp0,pp1,muC,muO,part);
    else if (wv == 1) do_set<1,MODE>(d,n,lane,ph0,ph1,pp0,pp1,muC,muO,part);
    else if (wv == 2) do_set<2,MODE>(d,n,lane,ph0,ph1,pp0,pp1,muC,muO,part);
    else if (wv == 3) do_set<3,MODE>(d,n,lane,ph0,ph1,pp0,pp1,muC,muO,part);
    else if (wv == 4) do_set<4,MODE>(d,n,lane,ph0,ph1,pp0,pp1,muC,muO,part);
    else if (wv == 5) do_set<5,MODE>(d,n,lane,ph0,ph1,pp0,pp1,muC,muO,part);
    else if (wv == 6) do_set<6,MODE>(d,n,lane,ph0,ph1,pp0,pp1,muC,muO,part);
    else              do_set<7,MODE>(d,n,lane,ph0,ph1,pp0,pp1,muC,muO,part);

    // -------- early-issue phase-B loads (complete during barrier drain) -----
    int t  = blockIdx.x*512 + tid;   // [0, NL)
    int z  = t & (LL-1);
    int n2 = t >> 4;
    int i2 = n2 >> 8;
    int j2 = n2 & (WW-1);
    float p0c = (float)pxCur[t];
    float p1c = (float)pxCur[NL + t];
    float p0u = (i2 > 0) ? (float)pxCur[t - WW*LL] : 0.0f;
    float p1l = (j2 > 0) ? (float)pxCur[NL + t - LL] : 0.0f;
    float ptc = (float)pt[t];
    float ptm = (z > 0) ? (float)pt[t - 1] : 0.0f;
    float uo  = (MODE == 0) ? f[n2] : u[t];

    __syncthreads();   // all staged partials visible

    // -------- reduce partials over h, store fp16 musum --------
    #pragma unroll
    for (int r = 0; r < 2; ++r) {
        int z2    = (tid >> 6) + r*8;
        int inner = tid & 63;
        float s = 0.0f;
        #pragma unroll
        for (int hh = 0; hh < 8; ++hh) s += part[hh*1024 + z2*64 + inner];
        int d2 = inner & 1, pix2 = inner >> 1;
        musum[(size_t)d2*NL + ((size_t)blockIdx.x*32 + pix2)*LL + z2] = (half_t)s;
    }

    // -------- phase B: primal u update (1 z per thread) --------
    {
        float d0 = ((i2 < HH-1) ? p0c : 0.0f) - p0u;
        float d1 = ((j2 < WW-1) ? p1c : 0.0f) - p1l;
        float dt = ((z < LL-1) ? ptc : 0.0f) - ptm;

        float Dv = uo + TAUU_F * ((d0 + d1) * 256.0f + dt * 16.0f);
        float un = clampf(Dv, 0.0f, 1.0f);
        if (z == 0)     un = 1.0f;
        if (z == LL-1)  un = 0.0f;
        if (last) out[t] = un;           // final iteration: write output directly
        else {
            u[t]    = un;
            ubar[t] = (half_t)(2.0f*un - uo);
        }

        if (MODE == 0) {   // nrj only at it=0 (it%10==0 with repeats=10)
            float v = fabsf(un - uo);
            #pragma unroll
            for (int off = 32; off > 0; off >>= 1) v += __shfl_down(v, off);
            if ((tid & 63) == 0) wsum[wv] = v;
            __syncthreads();
            if (tid == 0) {
                float s = 0.0f;
                #pragma unroll
                for (int q = 0; q < 8; ++q) s += wsum[q];
                atomicAdd(nrj, s);
            }
        }
    }
}

// ---------------- tail scalars ----------------------------------------------
__global__ void k_final(const float* __restrict__ nrj, float* __restrict__ out_tail)
{
    if (threadIdx.x == 0) {
        float e = *nrj;
        out_tail[0] = e;
        out_tail[1] = e * (1.0f/1048576.0f);   // nrj / (H*W*1*l)
        out_tail[2] = 0.0f;
    }
}

extern "C" void kernel_launch(void* const* d_in, const int* in_sizes, int n_in,
                              void* d_out, int out_size, void* d_ws, size_t ws_size,
                              hipStream_t stream)
{
    const float* f = (const float*)d_in[0];
    float* out = (float*)d_out;

    char* w = (char*)d_ws;
    size_t off = 0;
    auto allocf = [&](size_t nfloats) {
        float* p = (float*)(w + off);
        off += nfloats * sizeof(float);
        return p;
    };
    auto alloch = [&](size_t nhalf) {
        half_t* p = (half_t*)(w + off);
        off += nhalf * sizeof(half_t);
        return p;
    };
    half_t* muA    = alloch((size_t)NPIX * PP2);   // 35.7 MB
    half_t* muB    = alloch((size_t)NPIX * PP2);   // 35.7 MB
    half_t* musum  = alloch(2*(size_t)NL);         // 4.2 MB
    half_t* pxA    = alloch(2*(size_t)NL);         // 4.2 MB
    half_t* pxB    = alloch(2*(size_t)NL);         // 4.2 MB
    half_t* pt     = alloch((size_t)NL);           // 2.1 MB
    half_t* ubar   = alloch((size_t)NL);           // 2.1 MB
    float*  u      = allocf((size_t)NL);           // 4.2 MB
    float*  nrj    = allocf(64);
    (void)ws_size; (void)in_sizes; (void)n_in; (void)out_size;

    // No memset/init: it=0 fully specialized (state analytically zero, never
    // read); it=1 skips the muO read (poisoned buffer fully overwritten at
    // it=0/1). Every buffer's first access per call is a write.
    half_t* pxC = pxA;  // px(it)
    half_t* pxO = pxB;  // px(it-1)
    half_t* mC  = muA;  // mu_{k-1}
    half_t* mO  = muB;  // mu_{k-2} -> becomes mu_k
    for (int it = 0; it < 10; ++it) {
        int last = (it == 9) ? 1 : 0;
        if (it == 0) {
            k_prox<0><<<2*NPIX/256, 256, 0, stream>>>(f, ubar, pxO, pxC, pt, musum, nrj);
            k_smu_u<0><<<NPIX/32, 512, 0, stream>>>(f, pxC, pxO, pt, mC, mO, musum, u, ubar, out, nrj, last);
        } else if (it == 1) {
            k_prox<1><<<2*NPIX/256, 256, 0, stream>>>(f, ubar, pxO, pxC, pt, musum, nrj);
            k_smu_u<1><<<NPIX/32, 512, 0, stream>>>(f, pxC, pxO, pt, mC, mO, musum, u, ubar, out, nrj, last);
        } else {
            k_prox<1><<<2*NPIX/256, 256, 0, stream>>>(f, ubar, pxO, pxC, pt, musum, nrj);
            k_smu_u<2><<<NPIX/32, 512, 0, stream>>>(f, pxC, pxO, pt, mC, mO, musum, u, ubar, out, nrj, last);
        }
        { half_t* tmp = pxC; pxC = pxO; pxO = tmp; }
        { half_t* tmp = mC;  mC  = mO;  mO  = tmp; }  // mO-buffer holds mu_k
    }

    k_final<<<1, 64, 0, stream>>>(nrj, out + NL);
}

// Round 12
// 429.639 us; speedup vs baseline: 1.9082x; 1.9082x over previous
//
#include <hip/hip_runtime.h>

#define HH 256
#define WW 256
#define NPIX (HH*WW)
#define LL 16
#define NL (NPIX*LL)
#define PP 136
#define PP2 (PP*2)

typedef _Float16 half_t;
typedef __attribute__((ext_vector_type(8))) _Float16 half8;

// constants (double-evaluated, cast to float -- matches JAX weak-typed scalars)
static constexpr float SIGMAP_F = (float)((1.0/256.0)/(3.0+16.0)); // res/(3+l)
static constexpr float TAUU_F   = (float)((1.0/256.0)/6.0);        // res/6
static constexpr float TAU_F    = (float)(1.0/36.0);               // 1/(2+136/4)

__device__ __forceinline__ float clampf(float x, float lo, float hi){
    return fminf(fmaxf(x, lo), hi);
}
__device__ __forceinline__ half8 h8zero() {
    half8 v;
    #pragma unroll
    for (int i = 0; i < 8; ++i) v[i] = (half_t)0.0f;
    return v;
}

// ---------------- prox: dual p update, vectorized half8 ----------------------
// thread = (pixel n, z-half hf): 8 consecutive z. All fp16 state loaded as
// half8 (G13). Math fp32, per-z.
// MODE 0 (it=0): state analytically zero, reads ONLY f (z-uniform gradients).
template<int MODE>
__global__ __launch_bounds__(256) void k_prox(const float* __restrict__ f,
    const half_t* __restrict__ ubar,
    const half_t* __restrict__ pxOld,   // px(it-1)
    half_t* __restrict__ pxCur,         // px(it) out
    half_t* __restrict__ pt,            // in-place
    const half_t* __restrict__ musum,   // [d][n][z]
    float* __restrict__ nrj)
{
    int t = blockIdx.x*256 + threadIdx.x;   // [0, 2*NPIX)
    if (MODE == 0 && t == 0) *nrj = 0.0f;
    int n  = t >> 1;
    int hf = t & 1;
    int z0 = hf << 3;
    int i = n >> 8, j = n & (WW-1);
    bool iok = (i < HH-1), jok = (j < WW-1);
    size_t base = (size_t)n*LL + z0;

    float fv = f[n];
    float g0c = 0.0f, g1c = 0.0f;
    half8 ubv = h8zero(), ubi = h8zero(), ubj = h8zero();
    float ubz8 = 0.0f;
    half8 ms0v = h8zero(), ms1v = h8zero();
    half8 p0v  = h8zero(), p1v  = h8zero(), ptv = h8zero();
    if (MODE == 0) {
        g0c = iok ? (f[n + WW] - fv) * 256.0f : 0.0f;
        g1c = jok ? (f[n + 1]  - fv) * 256.0f : 0.0f;
    } else {
        ubv = *reinterpret_cast<const half8*>(ubar + base);
        if (iok) ubi = *reinterpret_cast<const half8*>(ubar + base + (size_t)WW*LL);
        if (jok) ubj = *reinterpret_cast<const half8*>(ubar + base + LL);
        if (hf == 0) ubz8 = (float)ubar[base + 8];
        ms0v = *reinterpret_cast<const half8*>(musum + base);
        ms1v = *reinterpret_cast<const half8*>(musum + NL + base);
        p0v  = *reinterpret_cast<const half8*>(pxOld + base);
        p1v  = *reinterpret_cast<const half8*>(pxOld + NL + base);
        ptv  = *reinterpret_cast<const half8*>(pt + base);
    }

    half8 o0, o1, opt;
    #pragma unroll
    for (int e = 0; e < 8; ++e) {
        int z = z0 + e;
        float ux0, ux1, ut;
        if (MODE == 0) {
            ux0 = SIGMAP_F * g0c;
            ux1 = SIGMAP_F * g1c;
            ut  = 0.0f;
        } else {
            float ub = (float)ubv[e];
            float g0 = iok ? ((float)ubi[e] - ub) * 256.0f : 0.0f;
            float g1 = jok ? ((float)ubj[e] - ub) * 256.0f : 0.0f;
            float ubn = (e < 7) ? (float)ubv[e+1] : ubz8;
            float gt = (z < LL-1) ? (ubn - ub) * 16.0f : 0.0f;
            ux0 = (float)p0v[e] + SIGMAP_F * (g0 + (float)ms0v[e]);
            ux1 = (float)p1v[e] + SIGMAP_F * (g1 + (float)ms1v[e]);
            ut  = (float)ptv[e] + SIGMAP_F * gt;
        }

        float klf = (float)(z + 1) * 0.0625f - fv;
        float pen = 0.5f * klf * klf;            // lmbda = 0.5

        float n2 = ux0*ux0 + ux1*ux1;
        float B  = 0.25f * n2 - pen;
        bool mask = ut < B;

        float px0 = ux0, px1 = ux1, ptn = ut;
        if (mask) {
            float y    = ut + pen;
            float norm = sqrtf(n2);
            float a    = 0.5f * norm;
            float b    = (2.0f/3.0f) * (1.0f - 0.5f*y);
            float v;
            if (b < 0.0f) {
                float sb  = sqrtf(-b);
                float sb3 = sb*sb*sb;
                float dd  = (a - sb3)*(a + sb3);
                if (dd < 0.0f) {
                    float ratio = clampf(a / sb3, -1.0f, 1.0f);
                    v = 2.0f * sb * cosf(acosf(ratio) * (1.0f/3.0f));
                } else {
                    float c = cbrtf(a + sqrtf(dd));
                    v = (c == 0.0f) ? 0.0f : (c - b/c);
                }
            } else {
                float dd = a*a + b*b*b;          // >= 0
                float c  = cbrtf(a + sqrtf(dd));
                v = (c == 0.0f) ? 0.0f : (c - b/c);
            }
            if (norm == 0.0f) { px0 = 0.0f; px1 = 0.0f; }
            else              { float s = 2.0f*v/norm; px0 = s*ux0; px1 = s*ux1; }
            ptn = 0.25f*(px0*px0 + px1*px1) - pen;
        }
        o0[e]  = (half_t)px0;
        o1[e]  = (half_t)px1;
        opt[e] = (half_t)ptn;
    }
    *reinterpret_cast<half8*>(pxCur + base)      = o0;
    *reinterpret_cast<half8*>(pxCur + NL + base) = o1;
    *reinterpret_cast<half8*>(pt + base)         = opt;
}

// ---------------- fused s/mu update + primal u update ------------------------
// sx ELIMINATED: sx_{k-1} = (mu_{k-1}-mu_{k-2})/tau + t_prev (t_prev from
// pxOld). mubar = 2*mu_{k-1}-mu_{k-2}; mu ping-pong, only mu_k written.
// MODE 0: mu,pxOld zero (regs zero-init, loads skipped); MODE 1: muO zero.
// C[16] accumulator ELIMINATED via descending suffix-sum pass over mn regs.
// NOTE on launch bounds: (512,8) forced VGPR<=64 -> compiler spilled to 32
// VGPR + scratch, 240 MB of spill WRITE traffic, 2x regression (round 11).
// (512,4) caps at 128; compiler lands ~60-70 with zero spill.
template<int H, int MODE>
__device__ __forceinline__ void do_set(int d, int n, int lane,
    half8 ph0, half8 ph1, half8 pp0, half8 pp1,
    const half_t* __restrict__ muC,   // mu_{k-1} (read, MODE>=1)
    half_t* __restrict__ muO,         // mu_{k-2} (read, MODE 2) -> mu_k (write)
    float* __restrict__ part)
{
    constexpr size_t setbase = (size_t)H * 17 * 2 * NPIX;
    const size_t vb   = setbase + (size_t)n*16 + (size_t)d*8;    // chunk0
    const size_t vb1  = vb + (size_t)16*NPIX;                    // chunk1
    const size_t tail = setbase + (size_t)32*NPIX + (size_t)n*2 + (size_t)d;

    half8 mCv0 = h8zero(), mCv1 = h8zero(), mOv0 = h8zero(), mOv1 = h8zero();
    float mCT = 0.0f, mOT = 0.0f;
    if (MODE >= 1) {
        mCv0 = *reinterpret_cast<const half8*>(&muC[vb]);
        mCv1 = *reinterpret_cast<const half8*>(&muC[vb1]);
        mCT  = (float)muC[tail];
    }
    if (MODE == 2) {
        mOv0 = *reinterpret_cast<const half8*>(&muO[vb]);
        mOv1 = *reinterpret_cast<const half8*>(&muO[vb1]);
        mOT  = (float)muO[tail];
    }

    half8 muo0, muo1;
    half_t muoT = (half_t)0.0f;

    float tsum = 0.0f, tprev = 0.0f;
    #pragma unroll
    for (int q = 0; q < 17; ++q) {
        const int b = (q <= 15-H) ? H + q : q - 1;   // static under unroll
        float mC, mO;
        if (q < 8)       { mC=(float)mCv0[q];   mO=(float)mOv0[q]; }
        else if (q < 16) { mC=(float)mCv1[q-8]; mO=(float)mOv1[q-8]; }
        else             { mC=mCT;              mO=mOT; }

        if (q == 0 || q == 16-H) { tsum = 0.0f; tprev = 0.0f; }  // row start
        tsum  += (b < 8) ? (float)ph0[b] : (float)ph1[b-8];
        if (MODE >= 1)
            tprev += (b < 8) ? (float)pp0[b] : (float)pp1[b-8];

        // sx_{k-1} = (mu_{k-1}-mu_{k-2})/tau + t_prev ; mx = sx - mubar
        float sxp = (mC - mO) * 36.0f + tprev;
        float mx  = sxp - (2.0f*mC - mO);
        float mo  = __shfl_xor(mx, 1);
        float snorm = sqrtf(mx*mx + mo*mo);
        if (snorm > 25.6f) mx *= 0.1f / snorm;       // nu*H ; nu/snorm
        float mn = mC + TAU_F*(mx - tsum);

        if (q < 8)       muo0[q]   = (half_t)mn;
        else if (q < 16) muo1[q-8] = (half_t)mn;
        else             muoT      = (half_t)mn;
    }

    *reinterpret_cast<half8*>(&muO[vb])  = muo0;
    *reinterpret_cast<half8*>(&muO[vb1]) = muo1;
    muO[tail] = muoT;

    // suffix-sum pass: row H has b=z at q=z-H; row 15-H has b=z at q=z+1.
    float sA = 0.0f, sB = 0.0f;
    #pragma unroll
    for (int z = 15; z >= 0; --z) {
        float m = 0.0f;
        if (z >= H) {
            const int q = z - H;
            sA += (q < 8) ? (float)muo0[q] : (q < 16) ? (float)muo1[q-8] : (float)muoT;
            m += sA;
        }
        if (z >= 15-H) {
            const int q = z + 1;
            sB += (q < 8) ? (float)muo0[q] : (q < 16) ? (float)muo1[q-8] : (float)muoT;
            m += sB;
        }
        part[H*1024 + z*64 + lane] = m;
    }
}

template<int MODE>
__global__ __launch_bounds__(512, 4) void k_smu_u(
    const float* __restrict__ f,
    const half_t* __restrict__ pxCur,   // px(it)   [d][n][z] fp16
    const half_t* __restrict__ pxOld,   // px(it-1) (MODE>=1)
    const half_t* __restrict__ pt,
    const half_t* __restrict__ muC,     // mu_{k-1} (MODE>=1)
    half_t* __restrict__ muO,           // mu_{k-2} -> mu_k
    half_t* __restrict__ musum,         // [d][n][z] fp16 output
    float* __restrict__ u, half_t* __restrict__ ubar,
    float* __restrict__ out,            // final-iter u destination
    float* __restrict__ nrj, int last)
{
    __shared__ float part[8192];   // 32 KB: [h][z][lane], all slots written
    __shared__ float wsum[8];

    int tid  = threadIdx.x;
    int wv   = tid >> 6;          // wave id = row-set h (0..7)
    int lane = tid & 63;
    int pix  = lane >> 1;
    int d    = lane & 1;
    int n    = blockIdx.x*32 + pix;

    // -------- phase A inputs, packed half8 --------
    const half8* pv = reinterpret_cast<const half8*>(pxCur + (size_t)d*NL + (size_t)n*LL);
    half8 ph0 = pv[0], ph1 = pv[1];
    half8 pp0 = h8zero(), pp1 = h8zero();
    if (MODE >= 1) {
        const half8* ppv = reinterpret_cast<const half8*>(pxOld + (size_t)d*NL + (size_t)n*LL);
        pp0 = ppv[0]; pp1 = ppv[1];
    }

    // -------- phase A: s & mu (per wave = one row set) --------
    if      (wv == 0) do_set<0,MODE>(d,n,lane,ph0,ph1,pp0,pp1,muC,muO,part);
    else if (wv == 1) do_set<1,MODE>(d,n,lane,ph0,ph1,pp0,pp1,muC,muO,part);
    else if (wv == 2) do_set<2,MODE>(d,n,lane,ph0,ph1,pp0,pp1,muC,muO,part);
    else if (wv == 3) do_set<3,MODE>(d,n,lane,ph0,ph1,pp0,pp1,muC,muO,part);
    else if (wv == 4) do_set<4,MODE>(d,n,lane,ph0,ph1,pp0,pp1,muC,muO,part);
    else if (wv == 5) do_set<5,MODE>(d,n,lane,ph0,ph1,pp0,pp1,muC,muO,part);
    else if (wv == 6) do_set<6,MODE>(d,n,lane,ph0,ph1,pp0,pp1,muC,muO,part);
    else              do_set<7,MODE>(d,n,lane,ph0,ph1,pp0,pp1,muC,muO,part);

    // -------- early-issue phase-B loads (complete during barrier drain) -----
    int t  = blockIdx.x*512 + tid;   // [0, NL)
    int z  = t & (LL-1);
    int n2 = t >> 4;
    int i2 = n2 >> 8;
    int j2 = n2 & (WW-1);
    float p0c = (float)pxCur[t];
    float p1c = (float)pxCur[NL + t];
    float p0u = (i2 > 0) ? (float)pxCur[t - WW*LL] : 0.0f;
    float p1l = (j2 > 0) ? (float)pxCur[NL + t - LL] : 0.0f;
    float ptc = (float)pt[t];
    float ptm = (z > 0) ? (float)pt[t - 1] : 0.0f;
    float uo  = (MODE == 0) ? f[n2] : u[t];

    __syncthreads();   // all staged partials visible

    // -------- reduce partials over h, store fp16 musum --------
    #pragma unroll
    for (int r = 0; r < 2; ++r) {
        int z2    = (tid >> 6) + r*8;
        int inner = tid & 63;
        float s = 0.0f;
        #pragma unroll
        for (int hh = 0; hh < 8; ++hh) s += part[hh*1024 + z2*64 + inner];
        int d2 = inner & 1, pix2 = inner >> 1;
        musum[(size_t)d2*NL + ((size_t)blockIdx.x*32 + pix2)*LL + z2] = (half_t)s;
    }

    // -------- phase B: primal u update (1 z per thread) --------
    {
        float d0 = ((i2 < HH-1) ? p0c : 0.0f) - p0u;
        float d1 = ((j2 < WW-1) ? p1c : 0.0f) - p1l;
        float dt = ((z < LL-1) ? ptc : 0.0f) - ptm;

        float Dv = uo + TAUU_F * ((d0 + d1) * 256.0f + dt * 16.0f);
        float un = clampf(Dv, 0.0f, 1.0f);
        if (z == 0)     un = 1.0f;
        if (z == LL-1)  un = 0.0f;
        if (last) out[t] = un;           // final iteration: write output directly
        else {
            u[t]    = un;
            ubar[t] = (half_t)(2.0f*un - uo);
        }

        if (MODE == 0) {   // nrj only at it=0 (it%10==0 with repeats=10)
            float v = fabsf(un - uo);
            #pragma unroll
            for (int off = 32; off > 0; off >>= 1) v += __shfl_down(v, off);
            if ((tid & 63) == 0) wsum[wv] = v;
            __syncthreads();
            if (tid == 0) {
                float s = 0.0f;
                #pragma unroll
                for (int q = 0; q < 8; ++q) s += wsum[q];
                atomicAdd(nrj, s);
            }
        }
    }
}

// ---------------- tail scalars ----------------------------------------------
__global__ void k_final(const float* __restrict__ nrj, float* __restrict__ out_tail)
{
    if (threadIdx.x == 0) {
        float e = *nrj;
        out_tail[0] = e;
        out_tail[1] = e * (1.0f/1048576.0f);   // nrj / (H*W*1*l)
        out_tail[2] = 0.0f;
    }
}

extern "C" void kernel_launch(void* const* d_in, const int* in_sizes, int n_in,
                              void* d_out, int out_size, void* d_ws, size_t ws_size,
                              hipStream_t stream)
{
    const float* f = (const float*)d_in[0];
    float* out = (float*)d_out;

    char* w = (char*)d_ws;
    size_t off = 0;
    auto allocf = [&](size_t nfloats) {
        float* p = (float*)(w + off);
        off += nfloats * sizeof(float);
        return p;
    };
    auto alloch = [&](size_t nhalf) {
        half_t* p = (half_t*)(w + off);
        off += nhalf * sizeof(half_t);
        return p;
    };
    half_t* muA    = alloch((size_t)NPIX * PP2);   // 35.7 MB
    half_t* muB    = alloch((size_t)NPIX * PP2);   // 35.7 MB
    half_t* musum  = alloch(2*(size_t)NL);         // 4.2 MB
    half_t* pxA    = alloch(2*(size_t)NL);         // 4.2 MB
    half_t* pxB    = alloch(2*(size_t)NL);         // 4.2 MB
    half_t* pt     = alloch((size_t)NL);           // 2.1 MB
    half_t* ubar   = alloch((size_t)NL);           // 2.1 MB
    float*  u      = allocf((size_t)NL);           // 4.2 MB
    float*  nrj    = allocf(64);
    (void)ws_size; (void)in_sizes; (void)n_in; (void)out_size;

    // No memset/init: it=0 fully specialized (state analytically zero, never
    // read); it=1 skips the muO read (poisoned buffer fully overwritten at
    // it=0/1). Every buffer's first access per call is a write.
    half_t* pxC = pxA;  // px(it)
    half_t* pxO = pxB;  // px(it-1)
    half_t* mC  = muA;  // mu_{k-1}
    half_t* mO  = muB;  // mu_{k-2} -> becomes mu_k
    for (int it = 0; it < 10; ++it) {
        int last = (it == 9) ? 1 : 0;
        if (it == 0) {
            k_prox<0><<<2*NPIX/256, 256, 0, stream>>>(f, ubar, pxO, pxC, pt, musum, nrj);
            k_smu_u<0><<<NPIX/32, 512, 0, stream>>>(f, pxC, pxO, pt, mC, mO, musum, u, ubar, out, nrj, last);
        } else if (it == 1) {
            k_prox<1><<<2*NPIX/256, 256, 0, stream>>>(f, ubar, pxO, pxC, pt, musum, nrj);
            k_smu_u<1><<<NPIX/32, 512, 0, stream>>>(f, pxC, pxO, pt, mC, mO, musum, u, ubar, out, nrj, last);
        } else {
            k_prox<1><<<2*NPIX/256, 256, 0, stream>>>(f, ubar, pxO, pxC, pt, musum, nrj);
            k_smu_u<2><<<NPIX/32, 512, 0, stream>>>(f, pxC, pxO, pt, mC, mO, musum, u, ubar, out, nrj, last);
        }
        { half_t* tmp = pxC; pxC = pxO; pxO = tmp; }
        { half_t* tmp = mC;  mC  = mO;  mO  = tmp; }  // mO-buffer holds mu_k
    }

    k_final<<<1, 64, 0, stream>>>(nrj, out + NL);
}

// Round 13
// 419.821 us; speedup vs baseline: 1.9528x; 1.0234x over previous
//
#include <hip/hip_runtime.h>

#define HH 256
#define WW 256
#define NPIX (HH*WW)
#define LL 16
#define NL (NPIX*LL)
#define PP 136
#define PP2 (PP*2)

typedef _Float16 half_t;
typedef __attribute__((ext_vector_type(8))) _Float16 half8;

// constants (double-evaluated, cast to float -- matches JAX weak-typed scalars)
static constexpr float SIGMAP_F = (float)((1.0/256.0)/(3.0+16.0)); // res/(3+l)
static constexpr float TAUU_F   = (float)((1.0/256.0)/6.0);        // res/6
static constexpr float TAU_F    = (float)(1.0/36.0);               // 1/(2+136/4)

__device__ __forceinline__ float clampf(float x, float lo, float hi){
    return fminf(fmaxf(x, lo), hi);
}
__device__ __forceinline__ half8 h8zero() {
    half8 v;
    #pragma unroll
    for (int i = 0; i < 8; ++i) v[i] = (half_t)0.0f;
    return v;
}

// ---------------- prox: dual p update, vectorized half8 ----------------------
// thread = (pixel n, z-half hf): 8 consecutive z. All fp16 state as half8.
// MODE 0 (it=0): state analytically zero, reads ONLY f.
template<int MODE>
__global__ __launch_bounds__(256) void k_prox(const float* __restrict__ f,
    const half_t* __restrict__ ubar,
    const half_t* __restrict__ pxOld,   // px(it-1)
    half_t* __restrict__ pxCur,         // px(it) out
    half_t* __restrict__ pt,            // in-place
    const half_t* __restrict__ musum,   // [d][n][z]
    float* __restrict__ nrj)
{
    int t = blockIdx.x*256 + threadIdx.x;   // [0, 2*NPIX)
    if (MODE == 0 && t == 0) *nrj = 0.0f;
    int n  = t >> 1;
    int hf = t & 1;
    int z0 = hf << 3;
    int i = n >> 8, j = n & (WW-1);
    bool iok = (i < HH-1), jok = (j < WW-1);
    size_t base = (size_t)n*LL + z0;

    float fv = f[n];
    float g0c = 0.0f, g1c = 0.0f;
    half8 ubv = h8zero(), ubi = h8zero(), ubj = h8zero();
    float ubz8 = 0.0f;
    half8 ms0v = h8zero(), ms1v = h8zero();
    half8 p0v  = h8zero(), p1v  = h8zero(), ptv = h8zero();
    if (MODE == 0) {
        g0c = iok ? (f[n + WW] - fv) * 256.0f : 0.0f;
        g1c = jok ? (f[n + 1]  - fv) * 256.0f : 0.0f;
    } else {
        ubv = *reinterpret_cast<const half8*>(ubar + base);
        if (iok) ubi = *reinterpret_cast<const half8*>(ubar + base + (size_t)WW*LL);
        if (jok) ubj = *reinterpret_cast<const half8*>(ubar + base + LL);
        if (hf == 0) ubz8 = (float)ubar[base + 8];
        ms0v = *reinterpret_cast<const half8*>(musum + base);
        ms1v = *reinterpret_cast<const half8*>(musum + NL + base);
        p0v  = *reinterpret_cast<const half8*>(pxOld + base);
        p1v  = *reinterpret_cast<const half8*>(pxOld + NL + base);
        ptv  = *reinterpret_cast<const half8*>(pt + base);
    }

    half8 o0, o1, opt;
    #pragma unroll
    for (int e = 0; e < 8; ++e) {
        int z = z0 + e;
        float ux0, ux1, ut;
        if (MODE == 0) {
            ux0 = SIGMAP_F * g0c;
            ux1 = SIGMAP_F * g1c;
            ut  = 0.0f;
        } else {
            float ub = (float)ubv[e];
            float g0 = iok ? ((float)ubi[e] - ub) * 256.0f : 0.0f;
            float g1 = jok ? ((float)ubj[e] - ub) * 256.0f : 0.0f;
            float ubn = (e < 7) ? (float)ubv[e+1] : ubz8;
            float gt = (z < LL-1) ? (ubn - ub) * 16.0f : 0.0f;
            ux0 = (float)p0v[e] + SIGMAP_F * (g0 + (float)ms0v[e]);
            ux1 = (float)p1v[e] + SIGMAP_F * (g1 + (float)ms1v[e]);
            ut  = (float)ptv[e] + SIGMAP_F * gt;
        }

        float klf = (float)(z + 1) * 0.0625f - fv;
        float pen = 0.5f * klf * klf;            // lmbda = 0.5

        float n2 = ux0*ux0 + ux1*ux1;
        float B  = 0.25f * n2 - pen;
        bool mask = ut < B;

        float px0 = ux0, px1 = ux1, ptn = ut;
        if (mask) {
            float y    = ut + pen;
            float norm = sqrtf(n2);
            float a    = 0.5f * norm;
            float b    = (2.0f/3.0f) * (1.0f - 0.5f*y);
            float v;
            if (b < 0.0f) {
                float sb  = sqrtf(-b);
                float sb3 = sb*sb*sb;
                float dd  = (a - sb3)*(a + sb3);
                if (dd < 0.0f) {
                    float ratio = clampf(a / sb3, -1.0f, 1.0f);
                    v = 2.0f * sb * cosf(acosf(ratio) * (1.0f/3.0f));
                } else {
                    float c = cbrtf(a + sqrtf(dd));
                    v = (c == 0.0f) ? 0.0f : (c - b/c);
                }
            } else {
                float dd = a*a + b*b*b;          // >= 0
                float c  = cbrtf(a + sqrtf(dd));
                v = (c == 0.0f) ? 0.0f : (c - b/c);
            }
            if (norm == 0.0f) { px0 = 0.0f; px1 = 0.0f; }
            else              { float s = 2.0f*v/norm; px0 = s*ux0; px1 = s*ux1; }
            ptn = 0.25f*(px0*px0 + px1*px1) - pen;
        }
        o0[e]  = (half_t)px0;
        o1[e]  = (half_t)px1;
        opt[e] = (half_t)ptn;
    }
    *reinterpret_cast<half8*>(pxCur + base)      = o0;
    *reinterpret_cast<half8*>(pxCur + NL + base) = o1;
    *reinterpret_cast<half8*>(pt + base)         = opt;
}

// element access helpers (k static under unroll)
#define PH(k)  ((k) < 8 ? (float)ph0[(k)] : (float)ph1[(k)-8])
#define PPV(k) ((k) < 8 ? (float)pp0[(k)] : (float)pp1[(k)-8])

// ---------------- fused s/mu update + primal u update ------------------------
// sx ELIMINATED: sx_{k-1} = (mu_{k-1}-mu_{k-2})/tau + t_prev (t_prev from
// pxOld). mubar = 2*mu_{k-1}-mu_{k-2}; mu ping-pong, only mu_k written.
// MODE 0: mu,pxOld zero; MODE 1: muO zero (poisoned buffer fully overwritten).
// DESCENDING-z combo order: for z=15..0 process (H,z) then (15-H,z). tsum/
// tprev update by SUBTRACTING p[z] from precomputed row totals; the musum
// suffix accumulators (sA,sB) and part[z] write happen in the same step --
// no second pass over muo registers (register-peak reduction; target: natural
// VGPR <= 64 for the 8-waves/SIMD occupancy step WITHOUT forcing bounds --
// round 11 showed (512,8) forces catastrophic spills).
// Storage q-mapping = this processing order (consistent across iterations).
template<int H, int MODE>
__device__ __forceinline__ void do_set(int d, int n, int lane,
    half8 ph0, half8 ph1, half8 pp0, half8 pp1,
    const half_t* __restrict__ muC,   // mu_{k-1} (read, MODE>=1)
    half_t* __restrict__ muO,         // mu_{k-2} (read, MODE 2) -> mu_k (write)
    float* __restrict__ part)
{
    constexpr size_t setbase = (size_t)H * 17 * 2 * NPIX;
    const size_t vb   = setbase + (size_t)n*16 + (size_t)d*8;    // chunk0
    const size_t vb1  = vb + (size_t)16*NPIX;                    // chunk1
    const size_t tail = setbase + (size_t)32*NPIX + (size_t)n*2 + (size_t)d;

    half8 mCv0 = h8zero(), mCv1 = h8zero(), mOv0 = h8zero(), mOv1 = h8zero();
    float mCT = 0.0f, mOT = 0.0f;
    if (MODE >= 1) {
        mCv0 = *reinterpret_cast<const half8*>(&muC[vb]);
        mCv1 = *reinterpret_cast<const half8*>(&muC[vb1]);
        mCT  = (float)muC[tail];
    }
    if (MODE == 2) {
        mOv0 = *reinterpret_cast<const half8*>(&muO[vb]);
        mOv1 = *reinterpret_cast<const half8*>(&muO[vb1]);
        mOT  = (float)muO[tail];
    }

    // row totals (descending start): tsA = sum p[H..15], tsB = sum p[15-H..15]
    float tsA = 0.0f, tsB = 0.0f, tpA = 0.0f, tpB = 0.0f;
    #pragma unroll
    for (int k = H; k < 16; ++k) tsA += PH(k);
    #pragma unroll
    for (int k = 15-H; k < 16; ++k) tsB += PH(k);
    if (MODE >= 1) {
        #pragma unroll
        for (int k = H; k < 16; ++k) tpA += PPV(k);
        #pragma unroll
        for (int k = 15-H; k < 16; ++k) tpB += PPV(k);
    }

    half8 muo0, muo1;
    half_t muoT = (half_t)0.0f;
    float sA = 0.0f, sB = 0.0f;
    int q = 0;

    #pragma unroll
    for (int z = 15; z >= 0; --z) {
        float m = 0.0f;
        // ---- task (H, z) ----
        if (z >= H) {
            float mn;
            if (MODE == 0) {
                mn = -TAU_F * tsA;
            } else {
                float mC, mO;
                if (q < 8)       { mC=(float)mCv0[q];   mO=(float)mOv0[q]; }
                else if (q < 16) { mC=(float)mCv1[q-8]; mO=(float)mOv1[q-8]; }
                else             { mC=mCT;              mO=mOT; }
                float sxp = (mC - mO) * 36.0f + tpA;
                float mx  = sxp - (2.0f*mC - mO);
                float mo  = __shfl_xor(mx, 1);
                float snorm = sqrtf(mx*mx + mo*mo);
                if (snorm > 25.6f) mx *= 0.1f / snorm;   // nu*H ; nu/snorm
                mn = mC + TAU_F*(mx - tsA);
            }
            if (q < 8)       muo0[q]   = (half_t)mn;
            else if (q < 16) muo1[q-8] = (half_t)mn;
            else             muoT      = (half_t)mn;
            sA += mn;
            m  += sA;
            ++q;
        }
        // ---- task (15-H, z) ----
        if (z >= 15-H) {
            float mn;
            if (MODE == 0) {
                mn = -TAU_F * tsB;
            } else {
                float mC, mO;
                if (q < 8)       { mC=(float)mCv0[q];   mO=(float)mOv0[q]; }
                else if (q < 16) { mC=(float)mCv1[q-8]; mO=(float)mOv1[q-8]; }
                else             { mC=mCT;              mO=mOT; }
                float sxp = (mC - mO) * 36.0f + tpB;
                float mx  = sxp - (2.0f*mC - mO);
                float mo  = __shfl_xor(mx, 1);
                float snorm = sqrtf(mx*mx + mo*mo);
                if (snorm > 25.6f) mx *= 0.1f / snorm;
                mn = mC + TAU_F*(mx - tsB);
            }
            if (q < 8)       muo0[q]   = (half_t)mn;
            else if (q < 16) muo1[q-8] = (half_t)mn;
            else             muoT      = (half_t)mn;
            sB += mn;
            m  += sB;
            ++q;
        }
        // shrink row sums for next z
        if (z >= H+1) {
            tsA -= PH(z);
            if (MODE >= 1) tpA -= PPV(z);
        }
        if (z >= 15-H+1) {
            tsB -= PH(z);
            if (MODE >= 1) tpB -= PPV(z);
        }
        part[H*1024 + z*64 + lane] = m;
    }

    *reinterpret_cast<half8*>(&muO[vb])  = muo0;
    *reinterpret_cast<half8*>(&muO[vb1]) = muo1;
    muO[tail] = muoT;
}

template<int MODE>
__global__ __launch_bounds__(512, 4) void k_smu_u(
    const float* __restrict__ f,
    const half_t* __restrict__ pxCur,   // px(it)   [d][n][z] fp16
    const half_t* __restrict__ pxOld,   // px(it-1) (MODE>=1)
    const half_t* __restrict__ pt,
    const half_t* __restrict__ muC,     // mu_{k-1} (MODE>=1)
    half_t* __restrict__ muO,           // mu_{k-2} -> mu_k
    half_t* __restrict__ musum,         // [d][n][z] fp16 output
    float* __restrict__ u, half_t* __restrict__ ubar,
    float* __restrict__ out,            // final-iter u destination
    float* __restrict__ nrj, int last)
{
    __shared__ float part[8192];   // 32 KB: [h][z][lane], all slots written
    __shared__ float wsum[8];

    int tid  = threadIdx.x;
    int wv   = tid >> 6;          // wave id = row-set h (0..7)
    int lane = tid & 63;
    int pix  = lane >> 1;
    int d    = lane & 1;
    int n    = blockIdx.x*32 + pix;

    // -------- phase A inputs, packed half8 --------
    const half8* pv = reinterpret_cast<const half8*>(pxCur + (size_t)d*NL + (size_t)n*LL);
    half8 ph0 = pv[0], ph1 = pv[1];
    half8 pp0 = h8zero(), pp1 = h8zero();
    if (MODE >= 1) {
        const half8* ppv = reinterpret_cast<const half8*>(pxOld + (size_t)d*NL + (size_t)n*LL);
        pp0 = ppv[0]; pp1 = ppv[1];
    }

    // -------- phase A: s & mu (per wave = one row set) --------
    if      (wv == 0) do_set<0,MODE>(d,n,lane,ph0,ph1,pp0,pp1,muC,muO,part);
    else if (wv == 1) do_set<1,MODE>(d,n,lane,ph0,ph1,pp0,pp1,muC,muO,part);
    else if (wv == 2) do_set<2,MODE>(d,n,lane,ph0,ph1,pp0,pp1,muC,muO,part);
    else if (wv == 3) do_set<3,MODE>(d,n,lane,ph0,ph1,pp0,pp1,muC,muO,part);
    else if (wv == 4) do_set<4,MODE>(d,n,lane,ph0,ph1,pp0,pp1,muC,muO,part);
    else if (wv == 5) do_set<5,MODE>(d,n,lane,ph0,ph1,pp0,pp1,muC,muO,part);
    else if (wv == 6) do_set<6,MODE>(d,n,lane,ph0,ph1,pp0,pp1,muC,muO,part);
    else              do_set<7,MODE>(d,n,lane,ph0,ph1,pp0,pp1,muC,muO,part);

    __syncthreads();   // all staged partials visible

    // -------- phase-B loads (issue now; overlap the LDS reduce below) -------
    int t  = blockIdx.x*512 + tid;   // [0, NL)
    int z  = t & (LL-1);
    int n2 = t >> 4;
    int i2 = n2 >> 8;
    int j2 = n2 & (WW-1);
    float p0c = (float)pxCur[t];
    float p1c = (float)pxCur[NL + t];
    float p0u = (i2 > 0) ? (float)pxCur[t - WW*LL] : 0.0f;
    float p1l = (j2 > 0) ? (float)pxCur[NL + t - LL] : 0.0f;
    float ptc = (float)pt[t];
    float ptm = (z > 0) ? (float)pt[t - 1] : 0.0f;
    float uo  = (MODE == 0) ? f[n2] : u[t];

    // -------- reduce partials over h, store fp16 musum --------
    #pragma unroll
    for (int r = 0; r < 2; ++r) {
        int z2    = (tid >> 6) + r*8;
        int inner = tid & 63;
        float s = 0.0f;
        #pragma unroll
        for (int hh = 0; hh < 8; ++hh) s += part[hh*1024 + z2*64 + inner];
        int d2 = inner & 1, pix2 = inner >> 1;
        musum[(size_t)d2*NL + ((size_t)blockIdx.x*32 + pix2)*LL + z2] = (half_t)s;
    }

    // -------- phase B: primal u update (1 z per thread) --------
    {
        float d0 = ((i2 < HH-1) ? p0c : 0.0f) - p0u;
        float d1 = ((j2 < WW-1) ? p1c : 0.0f) - p1l;
        float dt = ((z < LL-1) ? ptc : 0.0f) - ptm;

        float Dv = uo + TAUU_F * ((d0 + d1) * 256.0f + dt * 16.0f);
        float un = clampf(Dv, 0.0f, 1.0f);
        if (z == 0)     un = 1.0f;
        if (z == LL-1)  un = 0.0f;
        if (last) out[t] = un;           // final iteration: write output directly
        else {
            u[t]    = un;
            ubar[t] = (half_t)(2.0f*un - uo);
        }

        if (MODE == 0) {   // nrj only at it=0 (it%10==0 with repeats=10)
            float v = fabsf(un - uo);
            #pragma unroll
            for (int off = 32; off > 0; off >>= 1) v += __shfl_down(v, off);
            if ((tid & 63) == 0) wsum[wv] = v;
            __syncthreads();
            if (tid == 0) {
                float s = 0.0f;
                #pragma unroll
                for (int q = 0; q < 8; ++q) s += wsum[q];
                atomicAdd(nrj, s);
            }
        }
    }
}

// ---------------- tail scalars ----------------------------------------------
__global__ void k_final(const float* __restrict__ nrj, float* __restrict__ out_tail)
{
    if (threadIdx.x == 0) {
        float e = *nrj;
        out_tail[0] = e;
        out_tail[1] = e * (1.0f/1048576.0f);   // nrj / (H*W*1*l)
        out_tail[2] = 0.0f;
    }
}

extern "C" void kernel_launch(void* const* d_in, const int* in_sizes, int n_in,
                              void* d_out, int out_size, void* d_ws, size_t ws_size,
                              hipStream_t stream)
{
    const float* f = (const float*)d_in[0];
    float* out = (float*)d_out;

    char* w = (char*)d_ws;
    size_t off = 0;
    auto allocf = [&](size_t nfloats) {
        float* p = (float*)(w + off);
        off += nfloats * sizeof(float);
        return p;
    };
    auto alloch = [&](size_t nhalf) {
        half_t* p = (half_t*)(w + off);
        off += nhalf * sizeof(half_t);
        return p;
    };
    half_t* muA    = alloch((size_t)NPIX * PP2);   // 35.7 MB
    half_t* muB    = alloch((size_t)NPIX * PP2);   // 35.7 MB
    half_t* musum  = alloch(2*(size_t)NL);         // 4.2 MB
    half_t* pxA    = alloch(2*(size_t)NL);         // 4.2 MB
    half_t* pxB    = alloch(2*(size_t)NL);         // 4.2 MB
    half_t* pt     = alloch((size_t)NL);           // 2.1 MB
    half_t* ubar   = alloch((size_t)NL);           // 2.1 MB
    float*  u      = allocf((size_t)NL);           // 4.2 MB
    float*  nrj    = allocf(64);
    (void)ws_size; (void)in_sizes; (void)n_in; (void)out_size;

    // No memset/init: it=0 fully specialized (state analytically zero, never
    // read); it=1 skips the muO read (poisoned buffer fully overwritten at
    // it=0/1). Every buffer's first access per call is a write.
    half_t* pxC = pxA;  // px(it)
    half_t* pxO = pxB;  // px(it-1)
    half_t* mC  = muA;  // mu_{k-1}
    half_t* mO  = muB;  // mu_{k-2} -> becomes mu_k
    for (int it = 0; it < 10; ++it) {
        int last = (it == 9) ? 1 : 0;
        if (it == 0) {
            k_prox<0><<<2*NPIX/256, 256, 0, stream>>>(f, ubar, pxO, pxC, pt, musum, nrj);
            k_smu_u<0><<<NPIX/32, 512, 0, stream>>>(f, pxC, pxO, pt, mC, mO, musum, u, ubar, out, nrj, last);
        } else if (it == 1) {
            k_prox<1><<<2*NPIX/256, 256, 0, stream>>>(f, ubar, pxO, pxC, pt, musum, nrj);
            k_smu_u<1><<<NPIX/32, 512, 0, stream>>>(f, pxC, pxO, pt, mC, mO, musum, u, ubar, out, nrj, last);
        } else {
            k_prox<1><<<2*NPIX/256, 256, 0, stream>>>(f, ubar, pxO, pxC, pt, musum, nrj);
            k_smu_u<2><<<NPIX/32, 512, 0, stream>>>(f, pxC, pxO, pt, mC, mO, musum, u, ubar, out, nrj, last);
        }
        { half_t* tmp = pxC; pxC = pxO; pxO = tmp; }
        { half_t* tmp = mC;  mC  = mO;  mO  = tmp; }  // mO-buffer holds mu_k
    }

    k_final<<<1, 64, 0, stream>>>(nrj, out + NL);
}

// Round 14
// 406.949 us; speedup vs baseline: 2.0145x; 1.0316x over previous
//
#include <hip/hip_runtime.h>

#define HH 256
#define WW 256
#define NPIX (HH*WW)
#define LL 16
#define NL (NPIX*LL)
#define PP 136
#define PP2 (PP*2)
#define NBLK (NPIX/32)   // 2048

typedef _Float16 half_t;
typedef __attribute__((ext_vector_type(8))) _Float16 half8;

// constants (double-evaluated, cast to float -- matches JAX weak-typed scalars)
static constexpr float SIGMAP_F = (float)((1.0/256.0)/(3.0+16.0)); // res/(3+l)
static constexpr float TAUU_F   = (float)((1.0/256.0)/6.0);        // res/6
static constexpr float TAU_F    = (float)(1.0/36.0);               // 1/(2+136/4)

__device__ __forceinline__ float clampf(float x, float lo, float hi){
    return fminf(fmaxf(x, lo), hi);
}
__device__ __forceinline__ half8 h8zero() {
    half8 v;
    #pragma unroll
    for (int i = 0; i < 8; ++i) v[i] = (half_t)0.0f;
    return v;
}

// ---------------- prox for one (pixel, z-half): 8 z's -----------------------
// PM 0 = it0 (all state analytically zero; reads ONLY f), PM 1 = steady.
template<int PM>
__device__ __forceinline__ void prox_one(const float* __restrict__ f, int np, int hf,
    const half_t* __restrict__ ubOld, const half_t* __restrict__ pxOld,
    const half_t* __restrict__ ptOld, const half_t* __restrict__ msOld,
    half8& o0, half8& o1, half8& opt)
{
    int z0 = hf << 3;
    int ip = np >> 8, jp = np & (WW-1);
    bool iok = (ip < HH-1), jok = (jp < WW-1);
    size_t base = (size_t)np*LL + z0;
    float fv = f[np];

    float g0c = 0.0f, g1c = 0.0f;
    half8 ubv = h8zero(), ubi = h8zero(), ubj = h8zero();
    float ubz8 = 0.0f;
    half8 ms0v = h8zero(), ms1v = h8zero();
    half8 p0v  = h8zero(), p1v  = h8zero(), ptv = h8zero();
    if (PM == 0) {
        g0c = iok ? (f[np + WW] - fv) * 256.0f : 0.0f;
        g1c = jok ? (f[np + 1]  - fv) * 256.0f : 0.0f;
    } else {
        ubv = *reinterpret_cast<const half8*>(ubOld + base);
        if (iok) ubi = *reinterpret_cast<const half8*>(ubOld + base + (size_t)WW*LL);
        if (jok) ubj = *reinterpret_cast<const half8*>(ubOld + base + LL);
        if (hf == 0) ubz8 = (float)ubOld[base + 8];
        ms0v = *reinterpret_cast<const half8*>(msOld + base);
        ms1v = *reinterpret_cast<const half8*>(msOld + NL + base);
        p0v  = *reinterpret_cast<const half8*>(pxOld + base);
        p1v  = *reinterpret_cast<const half8*>(pxOld + NL + base);
        ptv  = *reinterpret_cast<const half8*>(ptOld + base);
    }

    #pragma unroll
    for (int e = 0; e < 8; ++e) {
        int z = z0 + e;
        float ux0, ux1, ut;
        if (PM == 0) {
            ux0 = SIGMAP_F * g0c;
            ux1 = SIGMAP_F * g1c;
            ut  = 0.0f;
        } else {
            float ub = (float)ubv[e];
            float g0 = iok ? ((float)ubi[e] - ub) * 256.0f : 0.0f;
            float g1 = jok ? ((float)ubj[e] - ub) * 256.0f : 0.0f;
            float ubn = (e < 7) ? (float)ubv[e+1] : ubz8;
            float gt = (z < LL-1) ? (ubn - ub) * 16.0f : 0.0f;
            ux0 = (float)p0v[e] + SIGMAP_F * (g0 + (float)ms0v[e]);
            ux1 = (float)p1v[e] + SIGMAP_F * (g1 + (float)ms1v[e]);
            ut  = (float)ptv[e] + SIGMAP_F * gt;
        }

        float klf = (float)(z + 1) * 0.0625f - fv;
        float pen = 0.5f * klf * klf;            // lmbda = 0.5

        float n2 = ux0*ux0 + ux1*ux1;
        float B  = 0.25f * n2 - pen;
        bool mask = ut < B;

        float px0 = ux0, px1 = ux1, ptn = ut;
        if (mask) {
            float y    = ut + pen;
            float norm = sqrtf(n2);
            float a    = 0.5f * norm;
            float b    = (2.0f/3.0f) * (1.0f - 0.5f*y);
            float v;
            if (b < 0.0f) {
                float sb  = sqrtf(-b);
                float sb3 = sb*sb*sb;
                float dd  = (a - sb3)*(a + sb3);
                if (dd < 0.0f) {
                    float ratio = clampf(a / sb3, -1.0f, 1.0f);
                    v = 2.0f * sb * cosf(acosf(ratio) * (1.0f/3.0f));
                } else {
                    float c = cbrtf(a + sqrtf(dd));
                    v = (c == 0.0f) ? 0.0f : (c - b/c);
                }
            } else {
                float dd = a*a + b*b*b;          // >= 0
                float c  = cbrtf(a + sqrtf(dd));
                v = (c == 0.0f) ? 0.0f : (c - b/c);
            }
            if (norm == 0.0f) { px0 = 0.0f; px1 = 0.0f; }
            else              { float s = 2.0f*v/norm; px0 = s*ux0; px1 = s*ux1; }
            ptn = 0.25f*(px0*px0 + px1*px1) - pen;
        }
        o0[e]  = (half_t)px0;
        o1[e]  = (half_t)px1;
        opt[e] = (half_t)ptn;
    }
}

// element access helpers (k static under unroll)
#define PH(k)  ((k) < 8 ? (float)ph0[(k)] : (float)ph1[(k)-8])
#define PPV(k) ((k) < 8 ? (float)pp0[(k)] : (float)pp1[(k)-8])

// ---------------- s & mu update for one row set (round-13 logic) ------------
template<int H, int MODE>
__device__ __forceinline__ void do_set(int d, int n, int lane,
    half8 ph0, half8 ph1, half8 pp0, half8 pp1,
    const half_t* __restrict__ muC,   // mu_{k-1} (read, MODE>=1)
    half_t* __restrict__ muO,         // mu_{k-2} (read, MODE 2) -> mu_k (write)
    float* __restrict__ part)
{
    constexpr size_t setbase = (size_t)H * 17 * 2 * NPIX;
    const size_t vb   = setbase + (size_t)n*16 + (size_t)d*8;    // chunk0
    const size_t vb1  = vb + (size_t)16*NPIX;                    // chunk1
    const size_t tail = setbase + (size_t)32*NPIX + (size_t)n*2 + (size_t)d;

    half8 mCv0 = h8zero(), mCv1 = h8zero(), mOv0 = h8zero(), mOv1 = h8zero();
    float mCT = 0.0f, mOT = 0.0f;
    if (MODE >= 1) {
        mCv0 = *reinterpret_cast<const half8*>(&muC[vb]);
        mCv1 = *reinterpret_cast<const half8*>(&muC[vb1]);
        mCT  = (float)muC[tail];
    }
    if (MODE == 2) {
        mOv0 = *reinterpret_cast<const half8*>(&muO[vb]);
        mOv1 = *reinterpret_cast<const half8*>(&muO[vb1]);
        mOT  = (float)muO[tail];
    }

    // row totals (descending start): tsA = sum p[H..15], tsB = sum p[15-H..15]
    float tsA = 0.0f, tsB = 0.0f, tpA = 0.0f, tpB = 0.0f;
    #pragma unroll
    for (int k = H; k < 16; ++k) tsA += PH(k);
    #pragma unroll
    for (int k = 15-H; k < 16; ++k) tsB += PH(k);
    if (MODE >= 1) {
        #pragma unroll
        for (int k = H; k < 16; ++k) tpA += PPV(k);
        #pragma unroll
        for (int k = 15-H; k < 16; ++k) tpB += PPV(k);
    }

    half8 muo0, muo1;
    half_t muoT = (half_t)0.0f;
    float sA = 0.0f, sB = 0.0f;
    int q = 0;

    #pragma unroll
    for (int z = 15; z >= 0; --z) {
        float m = 0.0f;
        if (z >= H) {                      // task (H, z)
            float mn;
            if (MODE == 0) {
                mn = -TAU_F * tsA;
            } else {
                float mC, mO;
                if (q < 8)       { mC=(float)mCv0[q];   mO=(float)mOv0[q]; }
                else if (q < 16) { mC=(float)mCv1[q-8]; mO=(float)mOv1[q-8]; }
                else             { mC=mCT;              mO=mOT; }
                float sxp = (mC - mO) * 36.0f + tpA;
                float mx  = sxp - (2.0f*mC - mO);
                float mo  = __shfl_xor(mx, 1);
                float snorm = sqrtf(mx*mx + mo*mo);
                if (snorm > 25.6f) mx *= 0.1f / snorm;   // nu*H ; nu/snorm
                mn = mC + TAU_F*(mx - tsA);
            }
            if (q < 8)       muo0[q]   = (half_t)mn;
            else if (q < 16) muo1[q-8] = (half_t)mn;
            else             muoT      = (half_t)mn;
            sA += mn; m += sA; ++q;
        }
        if (z >= 15-H) {                   // task (15-H, z)
            float mn;
            if (MODE == 0) {
                mn = -TAU_F * tsB;
            } else {
                float mC, mO;
                if (q < 8)       { mC=(float)mCv0[q];   mO=(float)mOv0[q]; }
                else if (q < 16) { mC=(float)mCv1[q-8]; mO=(float)mOv1[q-8]; }
                else             { mC=mCT;              mO=mOT; }
                float sxp = (mC - mO) * 36.0f + tpB;
                float mx  = sxp - (2.0f*mC - mO);
                float mo  = __shfl_xor(mx, 1);
                float snorm = sqrtf(mx*mx + mo*mo);
                if (snorm > 25.6f) mx *= 0.1f / snorm;
                mn = mC + TAU_F*(mx - tsB);
            }
            if (q < 8)       muo0[q]   = (half_t)mn;
            else if (q < 16) muo1[q-8] = (half_t)mn;
            else             muoT      = (half_t)mn;
            sB += mn; m += sB; ++q;
        }
        if (z >= H+1) {
            tsA -= PH(z);
            if (MODE >= 1) tpA -= PPV(z);
        }
        if (z >= 15-H+1) {
            tsB -= PH(z);
            if (MODE >= 1) tpB -= PPV(z);
        }
        part[H*1024 + z*64 + lane] = m;
    }

    *reinterpret_cast<half8*>(&muO[vb])  = muo0;
    *reinterpret_cast<half8*>(&muO[vb1]) = muo1;
    muO[tail] = muoT;
}

// ---------------- fused iteration kernel -------------------------------------
// One kernel per solver iteration: prox (own 32 pixels + 33 halo, recomputed)
// -> barrier -> s/mu phase A (reads own px from LDS) -> barrier -> musum
// reduce + primal u update (phase B, all px/pt from LDS).
// Ping-pong buffers for px/pt/ubar/musum: prox reads only (it-1) versions, so
// no intra-kernel cross-block races (halo prox re-reads old state globally).
// MODE: 0 = it0 (state zero; nrj partials), 1 = it1 (muO poisoned, skip read),
// 2 = steady, 3 = LAST (phase A is dead code: mu_9/musum_9 feed only a prox_10
// that never runs -- skip all mu traffic and px/pt/musum global writes).
template<int MODE>
__global__ __launch_bounds__(512, 4) void k_iter(
    const float* __restrict__ f,
    const half_t* __restrict__ pxOld, half_t* __restrict__ pxCur,
    const half_t* __restrict__ ptOld, half_t* __restrict__ ptCur,
    const half_t* __restrict__ ubOld, half_t* __restrict__ ubCur,
    const half_t* __restrict__ msOld, half_t* __restrict__ msCur,
    const half_t* __restrict__ muC, half_t* __restrict__ muO,
    float* __restrict__ u, float* __restrict__ out,
    float* __restrict__ nrjPartial)
{
    __shared__ float part[(MODE <= 2) ? 8192 : 1];   // 32 KB (unused at MODE 3)
    __shared__ __align__(16) half_t lp0[64][24];     // px0: own 0..31, north 32..63
    __shared__ __align__(16) half_t lp1[33][24];     // px1: own 0..31, west 32
    __shared__ __align__(16) half_t lpt[32][24];     // pt : own
    __shared__ float wsum[8];

    int tid = threadIdx.x;
    int b   = blockIdx.x;
    int n0  = b << 5;             // first owned pixel (32 consecutive, same row)
    int i0  = n0 >> 8;
    int j0  = n0 & (WW-1);

    // -------- prox phase: 130 threads handle 65 (pixel, z-half) items --------
    if (tid < 130) {
        int pl, np; bool valid = true;
        int hf = tid & 1;
        if (tid < 64)       { pl = tid >> 1;           np = n0 + pl; }
        else if (tid < 128) { pl = 32 + ((tid-64)>>1); np = n0 + (pl-32) - WW; valid = (i0 > 0); }
        else                { pl = 64;                 np = n0 - 1;            valid = (j0 > 0); }
        if (valid) {
            half8 o0, o1, opt;
            prox_one<(MODE==0) ? 0 : 1>(f, np, hf, ubOld, pxOld, ptOld, msOld, o0, o1, opt);
            int z0v = hf << 3;
            if (pl < 64) *reinterpret_cast<half8*>(&lp0[pl][z0v]) = o0;
            if (pl < 32) {
                *reinterpret_cast<half8*>(&lp1[pl][z0v]) = o1;
                *reinterpret_cast<half8*>(&lpt[pl][z0v]) = opt;
                if (MODE <= 2) {   // next iteration consumes these
                    *reinterpret_cast<half8*>(pxCur + (size_t)np*LL + z0v)      = o0;
                    *reinterpret_cast<half8*>(pxCur + NL + (size_t)np*LL + z0v) = o1;
                    *reinterpret_cast<half8*>(ptCur + (size_t)np*LL + z0v)      = opt;
                }
            } else if (pl == 64) {
                *reinterpret_cast<half8*>(&lp1[32][z0v]) = o1;
            }
        }
    }

    // -------- phase-A pp load + phase-B u load (issue before barrier) --------
    int wv = tid >> 6, lane = tid & 63, pix = lane >> 1, d = lane & 1;
    int n  = n0 + pix;
    half8 pp0 = h8zero(), pp1 = h8zero();
    if (MODE == 1 || MODE == 2) {
        const half8* ppv = reinterpret_cast<const half8*>(pxOld + (size_t)d*NL + (size_t)n*LL);
        pp0 = ppv[0]; pp1 = ppv[1];
    }
    int t  = b*512 + tid;            // global (n,z): n2 = t>>4, z = t&15
    int z  = t & (LL-1);
    int n2 = t >> 4;
    int i2 = n2 >> 8;
    int j2 = n2 & (WW-1);
    float uo = (MODE == 0) ? f[n2] : u[t];

    __syncthreads();   // LDS px/pt visible

    // -------- phase A: s & mu (skipped entirely at MODE 3) --------
    if (MODE <= 2) {
        const half8* ls = (d == 0) ? reinterpret_cast<const half8*>(&lp0[pix][0])
                                   : reinterpret_cast<const half8*>(&lp1[pix][0]);
        half8 ph0 = ls[0], ph1 = ls[1];

        if      (wv == 0) do_set<0,MODE>(d,n,lane,ph0,ph1,pp0,pp1,muC,muO,part);
        else if (wv == 1) do_set<1,MODE>(d,n,lane,ph0,ph1,pp0,pp1,muC,muO,part);
        else if (wv == 2) do_set<2,MODE>(d,n,lane,ph0,ph1,pp0,pp1,muC,muO,part);
        else if (wv == 3) do_set<3,MODE>(d,n,lane,ph0,ph1,pp0,pp1,muC,muO,part);
        else if (wv == 4) do_set<4,MODE>(d,n,lane,ph0,ph1,pp0,pp1,muC,muO,part);
        else if (wv == 5) do_set<5,MODE>(d,n,lane,ph0,ph1,pp0,pp1,muC,muO,part);
        else if (wv == 6) do_set<6,MODE>(d,n,lane,ph0,ph1,pp0,pp1,muC,muO,part);
        else              do_set<7,MODE>(d,n,lane,ph0,ph1,pp0,pp1,muC,muO,part);

        __syncthreads();   // staged partials visible

        // -------- reduce partials over h, store fp16 musum --------
        #pragma unroll
        for (int r = 0; r < 2; ++r) {
            int z2    = (tid >> 6) + r*8;
            int inner = tid & 63;
            float s = 0.0f;
            #pragma unroll
            for (int hh = 0; hh < 8; ++hh) s += part[hh*1024 + z2*64 + inner];
            int d2 = inner & 1, pix2 = inner >> 1;
            msCur[(size_t)d2*NL + ((size_t)n0 + pix2)*LL + z2] = (half_t)s;
        }
    }

    // -------- phase B: primal u update (1 z per thread, all inputs LDS) ------
    {
        int pl2 = tid >> 4;
        float p0c = (float)lp0[pl2][z];
        float p1c = (float)lp1[pl2][z];
        float p0u = (i2 > 0) ? (float)lp0[32 + pl2][z] : 0.0f;
        float p1l = (j2 > 0) ? ((pl2 > 0) ? (float)lp1[pl2-1][z] : (float)lp1[32][z]) : 0.0f;
        float ptc = (float)lpt[pl2][z];
        float ptm = (z > 0) ? (float)lpt[pl2][z-1] : 0.0f;

        float d0 = ((i2 < HH-1) ? p0c : 0.0f) - p0u;
        float d1 = ((j2 < WW-1) ? p1c : 0.0f) - p1l;
        float dt = ((z < LL-1) ? ptc : 0.0f) - ptm;

        float Dv = uo + TAUU_F * ((d0 + d1) * 256.0f + dt * 16.0f);
        float un = clampf(Dv, 0.0f, 1.0f);
        if (z == 0)     un = 1.0f;
        if (z == LL-1)  un = 0.0f;
        if (MODE == 3) out[t] = un;      // final iteration: output directly
        else {
            u[t]     = un;
            ubCur[t] = (half_t)(2.0f*un - uo);
        }

        if (MODE == 0) {   // nrj only at it=0 (it%10==0 with repeats=10)
            float v = fabsf(un - uo);
            #pragma unroll
            for (int off = 32; off > 0; off >>= 1) v += __shfl_down(v, off);
            if ((tid & 63) == 0) wsum[wv] = v;
            __syncthreads();
            if (tid == 0) {
                float s = 0.0f;
                #pragma unroll
                for (int q2 = 0; q2 < 8; ++q2) s += wsum[q2];
                nrjPartial[b] = s;       // per-block partial; no atomics/zeroing
            }
        }
    }
}

// ---------------- tail: reduce nrj partials + scalars ------------------------
__global__ void k_final(const float* __restrict__ nrjPartial, float* __restrict__ out_tail)
{
    float s = 0.0f;
    for (int k = threadIdx.x; k < NBLK; k += 64) s += nrjPartial[k];
    #pragma unroll
    for (int off = 32; off > 0; off >>= 1) s += __shfl_down(s, off);
    if (threadIdx.x == 0) {
        out_tail[0] = s;
        out_tail[1] = s * (1.0f/1048576.0f);   // nrj / (H*W*1*l)
        out_tail[2] = 0.0f;
    }
}

extern "C" void kernel_launch(void* const* d_in, const int* in_sizes, int n_in,
                              void* d_out, int out_size, void* d_ws, size_t ws_size,
                              hipStream_t stream)
{
    const float* f = (const float*)d_in[0];
    float* out = (float*)d_out;

    char* w = (char*)d_ws;
    size_t off = 0;
    auto allocf = [&](size_t nfloats) {
        float* p = (float*)(w + off);
        off += nfloats * sizeof(float);
        return p;
    };
    auto alloch = [&](size_t nhalf) {
        half_t* p = (half_t*)(w + off);
        off += nhalf * sizeof(half_t);
        return p;
    };
    half_t* muA  = alloch((size_t)NPIX * PP2);   // 35.7 MB
    half_t* muB  = alloch((size_t)NPIX * PP2);   // 35.7 MB
    half_t* msA  = alloch(2*(size_t)NL);         // 4.2 MB
    half_t* msB  = alloch(2*(size_t)NL);
    half_t* pxA  = alloch(2*(size_t)NL);
    half_t* pxB  = alloch(2*(size_t)NL);
    half_t* ptA  = alloch((size_t)NL);           // 2.1 MB
    half_t* ptB  = alloch((size_t)NL);
    half_t* ubA  = alloch((size_t)NL);
    half_t* ubB  = alloch((size_t)NL);
    float*  u    = allocf((size_t)NL);           // 4.2 MB
    float*  nrjP = allocf(NBLK);
    (void)ws_size; (void)in_sizes; (void)n_in; (void)out_size;

    // No memset/init: it=0 fully specialized (MODE 0 reads only f); it=1 skips
    // the muO read (poisoned buffer fully overwritten at it=0/1); all other
    // buffers' first access is a write. nrj via per-block partials (all 2048
    // written at MODE 0).
    half_t *pxO = pxA, *pxC = pxB;
    half_t *ptO = ptA, *ptC = ptB;
    half_t *ubO = ubA, *ubC = ubB;
    half_t *msO = msA, *msC = msB;
    half_t *mC  = muA, *mO  = muB;
    for (int it = 0; it < 10; ++it) {
        if (it == 0)
            k_iter<0><<<NBLK, 512, 0, stream>>>(f, pxO, pxC, ptO, ptC, ubO, ubC,
                                                msO, msC, mC, mO, u, out, nrjP);
        else if (it == 1)
            k_iter<1><<<NBLK, 512, 0, stream>>>(f, pxO, pxC, ptO, ptC, ubO, ubC,
                                                msO, msC, mC, mO, u, out, nrjP);
        else if (it < 9)
            k_iter<2><<<NBLK, 512, 0, stream>>>(f, pxO, pxC, ptO, ptC, ubO, ubC,
                                                msO, msC, mC, mO, u, out, nrjP);
        else
            k_iter<3><<<NBLK, 512, 0, stream>>>(f, pxO, pxC, ptO, ptC, ubO, ubC,
                                                msO, msC, mC, mO, u, out, nrjP);
        { half_t* tmp = pxO; pxO = pxC; pxC = tmp; }
        { half_t* tmp = ptO; ptO = ptC; ptC = tmp; }
        { half_t* tmp = ubO; ubO = ubC; ubC = tmp; }
        { half_t* tmp = msO; msO = msC; msC = tmp; }
        { half_t* tmp = mC;  mC  = mO;  mO  = tmp; }   // mO-buffer holds mu_k
    }

    k_final<<<1, 64, 0, stream>>>(nrjP, out + NL);
}

// Round 15
// 371.826 us; speedup vs baseline: 2.2048x; 1.0945x over previous
//
#include <hip/hip_runtime.h>

#define HH 256
#define WW 256
#define NPIX (HH*WW)
#define LL 16
#define NL (NPIX*LL)
#define PP 136
#define PP2 (PP*2)
#define NBLK (NPIX/32)   // 2048

typedef _Float16 half_t;
typedef __attribute__((ext_vector_type(8))) _Float16 half8;
typedef __attribute__((ext_vector_type(4))) _Float16 half4;

// constants (double-evaluated, cast to float -- matches JAX weak-typed scalars)
static constexpr float SIGMAP_F = (float)((1.0/256.0)/(3.0+16.0)); // res/(3+l)
static constexpr float TAUU_F   = (float)((1.0/256.0)/6.0);        // res/6
static constexpr float TAU_F    = (float)(1.0/36.0);               // 1/(2+136/4)

__device__ __forceinline__ float clampf(float x, float lo, float hi){
    return fminf(fmaxf(x, lo), hi);
}
__device__ __forceinline__ half8 h8zero() {
    half8 v;
    #pragma unroll
    for (int i = 0; i < 8; ++i) v[i] = (half_t)0.0f;
    return v;
}
__device__ __forceinline__ half4 h4zero() {
    half4 v;
    #pragma unroll
    for (int i = 0; i < 4; ++i) v[i] = (half_t)0.0f;
    return v;
}

// ---------------- prox for one (pixel, z-quarter): 4 z's ---------------------
// PM 0 = it0 (all state analytically zero; reads ONLY f), PM 1 = steady.
// 4-z granularity spreads prox over 260 threads (vs 130 at 8-z) -- prox is
// the serial VALU-heavy phase (cbrt/acos/cos) and VALUBusy is ~50%.
template<int PM>
__device__ __forceinline__ void prox_q4(const float* __restrict__ f, int np, int z0,
    const half_t* __restrict__ ubOld, const half_t* __restrict__ pxOld,
    const half_t* __restrict__ ptOld, const half_t* __restrict__ msOld,
    half4& o0, half4& o1, half4& opt)
{
    int ip = np >> 8, jp = np & (WW-1);
    bool iok = (ip < HH-1), jok = (jp < WW-1);
    size_t base = (size_t)np*LL + z0;
    float fv = f[np];

    float g0c = 0.0f, g1c = 0.0f;
    half4 ubv = h4zero(), ubi = h4zero(), ubj = h4zero();
    float ubn4 = 0.0f;
    half4 ms0v = h4zero(), ms1v = h4zero();
    half4 p0v  = h4zero(), p1v  = h4zero(), ptv = h4zero();
    if (PM == 0) {
        g0c = iok ? (f[np + WW] - fv) * 256.0f : 0.0f;
        g1c = jok ? (f[np + 1]  - fv) * 256.0f : 0.0f;
    } else {
        ubv = *reinterpret_cast<const half4*>(ubOld + base);
        if (iok) ubi = *reinterpret_cast<const half4*>(ubOld + base + (size_t)WW*LL);
        if (jok) ubj = *reinterpret_cast<const half4*>(ubOld + base + LL);
        if (z0 < 12) ubn4 = (float)ubOld[base + 4];
        ms0v = *reinterpret_cast<const half4*>(msOld + base);
        ms1v = *reinterpret_cast<const half4*>(msOld + NL + base);
        p0v  = *reinterpret_cast<const half4*>(pxOld + base);
        p1v  = *reinterpret_cast<const half4*>(pxOld + NL + base);
        ptv  = *reinterpret_cast<const half4*>(ptOld + base);
    }

    #pragma unroll
    for (int e = 0; e < 4; ++e) {
        int z = z0 + e;
        float ux0, ux1, ut;
        if (PM == 0) {
            ux0 = SIGMAP_F * g0c;
            ux1 = SIGMAP_F * g1c;
            ut  = 0.0f;
        } else {
            float ub = (float)ubv[e];
            float g0 = iok ? ((float)ubi[e] - ub) * 256.0f : 0.0f;
            float g1 = jok ? ((float)ubj[e] - ub) * 256.0f : 0.0f;
            float ubn = (e < 3) ? (float)ubv[e+1] : ubn4;
            float gt = (z < LL-1) ? (ubn - ub) * 16.0f : 0.0f;
            ux0 = (float)p0v[e] + SIGMAP_F * (g0 + (float)ms0v[e]);
            ux1 = (float)p1v[e] + SIGMAP_F * (g1 + (float)ms1v[e]);
            ut  = (float)ptv[e] + SIGMAP_F * gt;
        }

        float klf = (float)(z + 1) * 0.0625f - fv;
        float pen = 0.5f * klf * klf;            // lmbda = 0.5

        float n2 = ux0*ux0 + ux1*ux1;
        float B  = 0.25f * n2 - pen;
        bool mask = ut < B;

        float px0 = ux0, px1 = ux1, ptn = ut;
        if (mask) {
            float y    = ut + pen;
            float norm = sqrtf(n2);
            float a    = 0.5f * norm;
            float b    = (2.0f/3.0f) * (1.0f - 0.5f*y);
            float v;
            if (b < 0.0f) {
                float sb  = sqrtf(-b);
                float sb3 = sb*sb*sb;
                float dd  = (a - sb3)*(a + sb3);
                if (dd < 0.0f) {
                    float ratio = clampf(a / sb3, -1.0f, 1.0f);
                    v = 2.0f * sb * cosf(acosf(ratio) * (1.0f/3.0f));
                } else {
                    float c = cbrtf(a + sqrtf(dd));
                    v = (c == 0.0f) ? 0.0f : (c - b/c);
                }
            } else {
                float dd = a*a + b*b*b;          // >= 0
                float c  = cbrtf(a + sqrtf(dd));
                v = (c == 0.0f) ? 0.0f : (c - b/c);
            }
            if (norm == 0.0f) { px0 = 0.0f; px1 = 0.0f; }
            else              { float s = 2.0f*v/norm; px0 = s*ux0; px1 = s*ux1; }
            ptn = 0.25f*(px0*px0 + px1*px1) - pen;
        }
        o0[e]  = (half_t)px0;
        o1[e]  = (half_t)px1;
        opt[e] = (half_t)ptn;
    }
}

// element access helpers (k static under unroll)
#define PH(k)  ((k) < 8 ? (float)ph0[(k)] : (float)ph1[(k)-8])
#define PPV(k) ((k) < 8 ? (float)pp0[(k)] : (float)pp1[(k)-8])

// ---------------- s & mu update for one row set ------------------------------
// mu values are PRELOADED by the caller (hoisted before the prox phase so the
// 71 MB mu stream's latency hides under prox compute + barrier).
template<int H, int MODE>
__device__ __forceinline__ void do_set(int lane,
    half8 ph0, half8 ph1, half8 pp0, half8 pp1,
    half8 mCv0, half8 mCv1, float mCT,
    half8 mOv0, half8 mOv1, float mOT,
    half_t* __restrict__ muO, size_t vb, size_t vb1, size_t tailIx,
    float* __restrict__ part)
{
    // row totals (descending start): tsA = sum p[H..15], tsB = sum p[15-H..15]
    float tsA = 0.0f, tsB = 0.0f, tpA = 0.0f, tpB = 0.0f;
    #pragma unroll
    for (int k = H; k < 16; ++k) tsA += PH(k);
    #pragma unroll
    for (int k = 15-H; k < 16; ++k) tsB += PH(k);
    if (MODE >= 1) {
        #pragma unroll
        for (int k = H; k < 16; ++k) tpA += PPV(k);
        #pragma unroll
        for (int k = 15-H; k < 16; ++k) tpB += PPV(k);
    }

    half8 muo0, muo1;
    half_t muoT = (half_t)0.0f;
    float sA = 0.0f, sB = 0.0f;
    int q = 0;

    #pragma unroll
    for (int z = 15; z >= 0; --z) {
        float m = 0.0f;
        if (z >= H) {                      // task (H, z)
            float mn;
            if (MODE == 0) {
                mn = -TAU_F * tsA;
            } else {
                float mC, mO;
                if (q < 8)       { mC=(float)mCv0[q];   mO=(float)mOv0[q]; }
                else if (q < 16) { mC=(float)mCv1[q-8]; mO=(float)mOv1[q-8]; }
                else             { mC=mCT;              mO=mOT; }
                float sxp = (mC - mO) * 36.0f + tpA;
                float mx  = sxp - (2.0f*mC - mO);
                float mo  = __shfl_xor(mx, 1);
                float snorm = sqrtf(mx*mx + mo*mo);
                if (snorm > 25.6f) mx *= 0.1f / snorm;   // nu*H ; nu/snorm
                mn = mC + TAU_F*(mx - tsA);
            }
            if (q < 8)       muo0[q]   = (half_t)mn;
            else if (q < 16) muo1[q-8] = (half_t)mn;
            else             muoT      = (half_t)mn;
            sA += mn; m += sA; ++q;
        }
        if (z >= 15-H) {                   // task (15-H, z)
            float mn;
            if (MODE == 0) {
                mn = -TAU_F * tsB;
            } else {
                float mC, mO;
                if (q < 8)       { mC=(float)mCv0[q];   mO=(float)mOv0[q]; }
                else if (q < 16) { mC=(float)mCv1[q-8]; mO=(float)mOv1[q-8]; }
                else             { mC=mCT;              mO=mOT; }
                float sxp = (mC - mO) * 36.0f + tpB;
                float mx  = sxp - (2.0f*mC - mO);
                float mo  = __shfl_xor(mx, 1);
                float snorm = sqrtf(mx*mx + mo*mo);
                if (snorm > 25.6f) mx *= 0.1f / snorm;
                mn = mC + TAU_F*(mx - tsB);
            }
            if (q < 8)       muo0[q]   = (half_t)mn;
            else if (q < 16) muo1[q-8] = (half_t)mn;
            else             muoT      = (half_t)mn;
            sB += mn; m += sB; ++q;
        }
        if (z >= H+1)    tsA -= PH(z);
        if (z >= 15-H+1) tsB -= PH(z);
        if (MODE >= 1) {
            if (z >= H+1)    tpA -= PPV(z);
            if (z >= 15-H+1) tpB -= PPV(z);
        }
        part[H*1024 + z*64 + lane] = m;
    }

    *reinterpret_cast<half8*>(&muO[vb])  = muo0;
    *reinterpret_cast<half8*>(&muO[vb1]) = muo1;
    muO[tailIx] = muoT;
}

// ---------------- fused iteration kernel -------------------------------------
// MODE: 0 = it0 (state zero; nrj partials), 1 = it1 (muO poisoned, skip read),
// 2 = steady, 3 = LAST (phase A dead: skip all mu traffic + px/pt/ms writes).
// Load schedule: mu (71 MB, the dominant stream) + pp + u issue FIRST; their
// latency hides under the prox phase (260 threads) and the barrier.
template<int MODE>
__global__ __launch_bounds__(512, 4) void k_iter(
    const float* __restrict__ f,
    const half_t* __restrict__ pxOld, half_t* __restrict__ pxCur,
    const half_t* __restrict__ ptOld, half_t* __restrict__ ptCur,
    const half_t* __restrict__ ubOld, half_t* __restrict__ ubCur,
    const half_t* __restrict__ msOld, half_t* __restrict__ msCur,
    const half_t* __restrict__ muC, half_t* __restrict__ muO,
    float* __restrict__ u, float* __restrict__ out,
    float* __restrict__ nrjPartial)
{
    __shared__ float part[(MODE <= 2) ? 8192 : 1];   // 32 KB (unused at MODE 3)
    __shared__ __align__(16) half_t lp0[64][24];     // px0: own 0..31, north 32..63
    __shared__ __align__(16) half_t lp1[33][24];     // px1: own 0..31, west 32
    __shared__ __align__(16) half_t lpt[32][24];     // pt : own
    __shared__ float wsum[8];

    int tid = threadIdx.x;
    int b   = blockIdx.x;
    int n0  = b << 5;             // first owned pixel (32 consecutive, same row)
    int i0  = n0 >> 8;
    int j0  = n0 & (WW-1);

    int wv = tid >> 6, lane = tid & 63, pix = lane >> 1, d = lane & 1;
    int n  = n0 + pix;

    // -------- hoisted loads: mu (biggest stream) + pp + u, issued first ------
    size_t setbase = (size_t)wv * 17 * 2 * NPIX;
    size_t vb     = setbase + (size_t)n*16 + (size_t)d*8;
    size_t vb1    = vb + (size_t)16*NPIX;
    size_t tailIx = setbase + (size_t)32*NPIX + (size_t)n*2 + (size_t)d;
    half8 mCv0 = h8zero(), mCv1 = h8zero(), mOv0 = h8zero(), mOv1 = h8zero();
    float mCT = 0.0f, mOT = 0.0f;
    if (MODE == 1 || MODE == 2) {
        mCv0 = *reinterpret_cast<const half8*>(&muC[vb]);
        mCv1 = *reinterpret_cast<const half8*>(&muC[vb1]);
        mCT  = (float)muC[tailIx];
    }
    if (MODE == 2) {
        mOv0 = *reinterpret_cast<const half8*>(&muO[vb]);
        mOv1 = *reinterpret_cast<const half8*>(&muO[vb1]);
        mOT  = (float)muO[tailIx];
    }
    half8 pp0 = h8zero(), pp1 = h8zero();
    if (MODE == 1 || MODE == 2) {
        const half8* ppv = reinterpret_cast<const half8*>(pxOld + (size_t)d*NL + (size_t)n*LL);
        pp0 = ppv[0]; pp1 = ppv[1];
    }
    int t  = b*512 + tid;            // global (n,z): n2 = t>>4, z = t&15
    int z  = t & (LL-1);
    int n2 = t >> 4;
    int i2 = n2 >> 8;
    int j2 = n2 & (WW-1);
    float uo = (MODE == 0) ? f[n2] : u[t];

    // -------- prox phase: 260 threads, (pixel, z-quarter) --------
    if (tid < 260) {
        int pl = tid >> 2, qf = tid & 3, z0v = qf << 2;
        int np; bool valid = true;
        if (pl < 32)      np = n0 + pl;
        else if (pl < 64) { np = n0 + (pl-32) - WW; valid = (i0 > 0); }
        else              { np = n0 - 1;            valid = (j0 > 0); }
        if (valid) {
            half4 o0, o1, opt;
            prox_q4<(MODE==0) ? 0 : 1>(f, np, z0v, ubOld, pxOld, ptOld, msOld, o0, o1, opt);
            if (pl < 64) *reinterpret_cast<half4*>(&lp0[pl][z0v]) = o0;
            if (pl < 32) {
                *reinterpret_cast<half4*>(&lp1[pl][z0v]) = o1;
                *reinterpret_cast<half4*>(&lpt[pl][z0v]) = opt;
                if (MODE <= 2) {   // next iteration consumes these
                    *reinterpret_cast<half4*>(pxCur + (size_t)np*LL + z0v)      = o0;
                    *reinterpret_cast<half4*>(pxCur + NL + (size_t)np*LL + z0v) = o1;
                    *reinterpret_cast<half4*>(ptCur + (size_t)np*LL + z0v)      = opt;
                }
            } else if (pl == 64) {
                *reinterpret_cast<half4*>(&lp1[32][z0v]) = o1;
            }
        }
    }

    __syncthreads();   // LDS px/pt visible

    // -------- phase A: s & mu (skipped entirely at MODE 3) --------
    if (MODE <= 2) {
        const half8* ls = (d == 0) ? reinterpret_cast<const half8*>(&lp0[pix][0])
                                   : reinterpret_cast<const half8*>(&lp1[pix][0]);
        half8 ph0 = ls[0], ph1 = ls[1];

        if      (wv == 0) do_set<0,MODE>(lane,ph0,ph1,pp0,pp1,mCv0,mCv1,mCT,mOv0,mOv1,mOT,muO,vb,vb1,tailIx,part);
        else if (wv == 1) do_set<1,MODE>(lane,ph0,ph1,pp0,pp1,mCv0,mCv1,mCT,mOv0,mOv1,mOT,muO,vb,vb1,tailIx,part);
        else if (wv == 2) do_set<2,MODE>(lane,ph0,ph1,pp0,pp1,mCv0,mCv1,mCT,mOv0,mOv1,mOT,muO,vb,vb1,tailIx,part);
        else if (wv == 3) do_set<3,MODE>(lane,ph0,ph1,pp0,pp1,mCv0,mCv1,mCT,mOv0,mOv1,mOT,muO,vb,vb1,tailIx,part);
        else if (wv == 4) do_set<4,MODE>(lane,ph0,ph1,pp0,pp1,mCv0,mCv1,mCT,mOv0,mOv1,mOT,muO,vb,vb1,tailIx,part);
        else if (wv == 5) do_set<5,MODE>(lane,ph0,ph1,pp0,pp1,mCv0,mCv1,mCT,mOv0,mOv1,mOT,muO,vb,vb1,tailIx,part);
        else if (wv == 6) do_set<6,MODE>(lane,ph0,ph1,pp0,pp1,mCv0,mCv1,mCT,mOv0,mOv1,mOT,muO,vb,vb1,tailIx,part);
        else              do_set<7,MODE>(lane,ph0,ph1,pp0,pp1,mCv0,mCv1,mCT,mOv0,mOv1,mOT,muO,vb,vb1,tailIx,part);

        __syncthreads();   // staged partials visible

        // -------- reduce partials over h, store fp16 musum --------
        #pragma unroll
        for (int r = 0; r < 2; ++r) {
            int z2    = (tid >> 6) + r*8;
            int inner = tid & 63;
            float s = 0.0f;
            #pragma unroll
            for (int hh = 0; hh < 8; ++hh) s += part[hh*1024 + z2*64 + inner];
            int d2 = inner & 1, pix2 = inner >> 1;
            msCur[(size_t)d2*NL + ((size_t)n0 + pix2)*LL + z2] = (half_t)s;
        }
    }

    // -------- phase B: primal u update (1 z per thread, all inputs LDS) ------
    {
        int pl2 = tid >> 4;
        float p0c = (float)lp0[pl2][z];
        float p1c = (float)lp1[pl2][z];
        float p0u = (i2 > 0) ? (float)lp0[32 + pl2][z] : 0.0f;
        float p1l = (j2 > 0) ? ((pl2 > 0) ? (float)lp1[pl2-1][z] : (float)lp1[32][z]) : 0.0f;
        float ptc = (float)lpt[pl2][z];
        float ptm = (z > 0) ? (float)lpt[pl2][z-1] : 0.0f;

        float d0 = ((i2 < HH-1) ? p0c : 0.0f) - p0u;
        float d1 = ((j2 < WW-1) ? p1c : 0.0f) - p1l;
        float dt = ((z < LL-1) ? ptc : 0.0f) - ptm;

        float Dv = uo + TAUU_F * ((d0 + d1) * 256.0f + dt * 16.0f);
        float un = clampf(Dv, 0.0f, 1.0f);
        if (z == 0)     un = 1.0f;
        if (z == LL-1)  un = 0.0f;
        if (MODE == 3) out[t] = un;      // final iteration: output directly
        else {
            u[t]     = un;
            ubCur[t] = (half_t)(2.0f*un - uo);
        }

        if (MODE == 0) {   // nrj only at it=0 (it%10==0 with repeats=10)
            float v = fabsf(un - uo);
            #pragma unroll
            for (int off = 32; off > 0; off >>= 1) v += __shfl_down(v, off);
            if ((tid & 63) == 0) wsum[wv] = v;
            __syncthreads();
            if (tid == 0) {
                float s = 0.0f;
                #pragma unroll
                for (int q2 = 0; q2 < 8; ++q2) s += wsum[q2];
                nrjPartial[b] = s;       // per-block partial; no atomics/zeroing
            }
        }
    }
}

// ---------------- tail: reduce nrj partials + scalars ------------------------
__global__ void k_final(const float* __restrict__ nrjPartial, float* __restrict__ out_tail)
{
    float s = 0.0f;
    for (int k = threadIdx.x; k < NBLK; k += 64) s += nrjPartial[k];
    #pragma unroll
    for (int off = 32; off > 0; off >>= 1) s += __shfl_down(s, off);
    if (threadIdx.x == 0) {
        out_tail[0] = s;
        out_tail[1] = s * (1.0f/1048576.0f);   // nrj / (H*W*1*l)
        out_tail[2] = 0.0f;
    }
}

extern "C" void kernel_launch(void* const* d_in, const int* in_sizes, int n_in,
                              void* d_out, int out_size, void* d_ws, size_t ws_size,
                              hipStream_t stream)
{
    const float* f = (const float*)d_in[0];
    float* out = (float*)d_out;

    char* w = (char*)d_ws;
    size_t off = 0;
    auto allocf = [&](size_t nfloats) {
        float* p = (float*)(w + off);
        off += nfloats * sizeof(float);
        return p;
    };
    auto alloch = [&](size_t nhalf) {
        half_t* p = (half_t*)(w + off);
        off += nhalf * sizeof(half_t);
        return p;
    };
    half_t* muA  = alloch((size_t)NPIX * PP2);   // 35.7 MB
    half_t* muB  = alloch((size_t)NPIX * PP2);   // 35.7 MB
    half_t* msA  = alloch(2*(size_t)NL);         // 4.2 MB
    half_t* msB  = alloch(2*(size_t)NL);
    half_t* pxA  = alloch(2*(size_t)NL);
    half_t* pxB  = alloch(2*(size_t)NL);
    half_t* ptA  = alloch((size_t)NL);           // 2.1 MB
    half_t* ptB  = alloch((size_t)NL);
    half_t* ubA  = alloch((size_t)NL);
    half_t* ubB  = alloch((size_t)NL);
    float*  u    = allocf((size_t)NL);           // 4.2 MB
    float*  nrjP = allocf(NBLK);
    (void)ws_size; (void)in_sizes; (void)n_in; (void)out_size;

    // No memset/init: it=0 fully specialized (MODE 0 reads only f); it=1 skips
    // the muO read (poisoned buffer fully overwritten at it=0/1); all other
    // buffers' first access is a write. nrj via per-block partials.
    half_t *pxO = pxA, *pxC = pxB;
    half_t *ptO = ptA, *ptC = ptB;
    half_t *ubO = ubA, *ubC = ubB;
    half_t *msO = msA, *msC = msB;
    half_t *mC  = muA, *mO  = muB;
    for (int it = 0; it < 10; ++it) {
        if (it == 0)
            k_iter<0><<<NBLK, 512, 0, stream>>>(f, pxO, pxC, ptO, ptC, ubO, ubC,
                                                msO, msC, mC, mO, u, out, nrjP);
        else if (it == 1)
            k_iter<1><<<NBLK, 512, 0, stream>>>(f, pxO, pxC, ptO, ptC, ubO, ubC,
                                                msO, msC, mC, mO, u, out, nrjP);
        else if (it < 9)
            k_iter<2><<<NBLK, 512, 0, stream>>>(f, pxO, pxC, ptO, ptC, ubO, ubC,
                                                msO, msC, mC, mO, u, out, nrjP);
        else
            k_iter<3><<<NBLK, 512, 0, stream>>>(f, pxO, pxC, ptO, ptC, ubO, ubC,
                                                msO, msC, mC, mO, u, out, nrjP);
        { half_t* tmp = pxO; pxO = pxC; pxC = tmp; }
        { half_t* tmp = ptO; ptO = ptC; ptC = tmp; }
        { half_t* tmp = ubO; ubO = ubC; ubC = tmp; }
        { half_t* tmp = msO; msO = msC; msC = tmp; }
        { half_t* tmp = mC;  mC  = mO;  mO  = tmp; }   // mO-buffer holds mu_k
    }

    k_final<<<1, 64, 0, stream>>>(nrjP, out + NL);
}